// Round 1
// baseline (3414.220 us; speedup 1.0000x reference)
//
#include <hip/hip_runtime.h>
#include <math.h>

#define Bsz 512
#define Nc  81
#define Rtot (Bsz*Nc)     /* 41472 rows */
#define DEG 20
#define Edim 16
#define HD  96
#define NITER 4

__device__ __forceinline__ float sigf(float x){ return 1.0f/(1.0f+expf(-x)); }

/* ---------------- kernel A: embed + input MLP, init h,c ----------------
   block = 192 threads = 2 groups x 96 cols; each group does 4 rows. */
__global__ __launch_bounds__(192) void k_embed(
    const int* __restrict__ grids, const float* __restrict__ embw,
    const float* __restrict__ w1, const float* __restrict__ b1,
    const float* __restrict__ w2, const float* __restrict__ b2,
    const float* __restrict__ w3, const float* __restrict__ b3,
    const float* __restrict__ c0,
    float* __restrict__ X, float* __restrict__ H, float* __restrict__ C)
{
    __shared__ float e[2][4][Edim];
    __shared__ float a0[2][4][HD];
    __shared__ float a1[2][4][HD];
    const int tid = threadIdx.x;
    const int rg = tid / HD, c = tid - rg*HD;
    const int r0 = blockIdx.x*8 + rg*4;

    if (c < Edim) {
        #pragma unroll
        for (int rr=0;rr<4;rr++)
            e[rg][rr][c] = embw[grids[r0+rr]*Edim + c];
    }
    __syncthreads();
    float s0,s1,s2,s3;
    s0=s1=s2=s3=b1[c];
    #pragma unroll
    for (int k=0;k<Edim;k++){
        float w=w1[k*HD+c];
        s0+=e[rg][0][k]*w; s1+=e[rg][1][k]*w;
        s2+=e[rg][2][k]*w; s3+=e[rg][3][k]*w;
    }
    a0[rg][0][c]=fmaxf(s0,0.f); a0[rg][1][c]=fmaxf(s1,0.f);
    a0[rg][2][c]=fmaxf(s2,0.f); a0[rg][3][c]=fmaxf(s3,0.f);
    __syncthreads();
    s0=s1=s2=s3=b2[c];
    #pragma unroll 4
    for (int k=0;k<HD;k++){
        float w=w2[k*HD+c];
        s0+=a0[rg][0][k]*w; s1+=a0[rg][1][k]*w;
        s2+=a0[rg][2][k]*w; s3+=a0[rg][3][k]*w;
    }
    a1[rg][0][c]=fmaxf(s0,0.f); a1[rg][1][c]=fmaxf(s1,0.f);
    a1[rg][2][c]=fmaxf(s2,0.f); a1[rg][3][c]=fmaxf(s3,0.f);
    __syncthreads();
    s0=s1=s2=s3=b3[c];
    #pragma unroll 4
    for (int k=0;k<HD;k++){
        float w=w3[k*HD+c];
        s0+=a1[rg][0][k]*w; s1+=a1[rg][1][k]*w;
        s2+=a1[rg][2][k]*w; s3+=a1[rg][3][k]*w;
    }
    X[(r0+0)*HD+c]=s0; H[(r0+0)*HD+c]=s0; C[(r0+0)*HD+c]=c0[(r0+0)*HD+c];
    X[(r0+1)*HD+c]=s1; H[(r0+1)*HD+c]=s1; C[(r0+1)*HD+c]=c0[(r0+1)*HD+c];
    X[(r0+2)*HD+c]=s2; H[(r0+2)*HD+c]=s2; C[(r0+2)*HD+c]=c0[(r0+2)*HD+c];
    X[(r0+3)*HD+c]=s3; H[(r0+3)*HD+c]=s3; C[(r0+3)*HD+c]=c0[(r0+3)*HD+c];
}

/* ---------------- kernel B: A = h@fw1_top, Bm = h@fw1_bot ---------------- */
__global__ __launch_bounds__(192) void k_ab(
    const float* __restrict__ H, const float* __restrict__ fw1,
    float* __restrict__ A, float* __restrict__ Bm)
{
    __shared__ float hb[2][4][HD];
    const int tid=threadIdx.x; const int rg=tid/HD, c=tid-rg*HD;
    const int r0=blockIdx.x*8+rg*4;
    #pragma unroll
    for (int rr=0;rr<4;rr++) hb[rg][rr][c]=H[(r0+rr)*HD+c];
    __syncthreads();
    float a0=0,a1=0,a2=0,a3=0, q0=0,q1=0,q2=0,q3=0;
    #pragma unroll 4
    for (int k=0;k<HD;k++){
        float wt = fw1[k*HD+c];
        float wb = fw1[(HD+k)*HD+c];
        float h0=hb[rg][0][k], h1=hb[rg][1][k], h2=hb[rg][2][k], h3=hb[rg][3][k];
        a0+=h0*wt; a1+=h1*wt; a2+=h2*wt; a3+=h3*wt;
        q0+=h0*wb; q1+=h1*wb; q2+=h2*wb; q3+=h3*wb;
    }
    A [(r0+0)*HD+c]=a0; A [(r0+1)*HD+c]=a1; A [(r0+2)*HD+c]=a2; A [(r0+3)*HD+c]=a3;
    Bm[(r0+0)*HD+c]=q0; Bm[(r0+1)*HD+c]=q1; Bm[(r0+2)*HD+c]=q2; Bm[(r0+3)*HD+c]=q3;
}

/* ---------------- kernel C: edge message MLP (dominant) ----------------
   per node: acc = sum_d relu( relu(A_i + Bm_j + b1) @ w2 + b2 ); M = acc@w3 + 20*b3 */
__global__ __launch_bounds__(192) void k_edge(
    const float* __restrict__ A, const float* __restrict__ Bm,
    const int* __restrict__ nbr,
    const float* __restrict__ fb1, const float* __restrict__ fw2,
    const float* __restrict__ fb2, const float* __restrict__ fw3,
    const float* __restrict__ fb3,
    float* __restrict__ M)
{
    __shared__ float w2s[HD*HD];      /* 36 KB */
    __shared__ float x1s[2][4][HD];
    const int tid=threadIdx.x; const int rg=tid/HD, c=tid-rg*HD;
    const int r0=blockIdx.x*8+rg*4;

    for (int idx=tid; idx<HD*HD; idx+=192) w2s[idx]=fw2[idx];

    const float b1c = fb1[c];
    const float b2c = fb2[c];
    float areg[4];
    int   bI[4], iI[4];
    #pragma unroll
    for (int rr=0;rr<4;rr++){
        int r=r0+rr;
        areg[rr]=A[r*HD+c]+b1c;
        bI[rr]=r/Nc; iI[rr]=r-bI[rr]*Nc;
    }
    float acc0=0,acc1=0,acc2=0,acc3=0;
    __syncthreads();

    for (int d=0; d<DEG; d++){
        {
            int j0=nbr[iI[0]*DEG+d], j1=nbr[iI[1]*DEG+d], j2=nbr[iI[2]*DEG+d], j3=nbr[iI[3]*DEG+d];
            x1s[rg][0][c]=fmaxf(areg[0]+Bm[(bI[0]*Nc+j0)*HD+c],0.f);
            x1s[rg][1][c]=fmaxf(areg[1]+Bm[(bI[1]*Nc+j1)*HD+c],0.f);
            x1s[rg][2][c]=fmaxf(areg[2]+Bm[(bI[2]*Nc+j2)*HD+c],0.f);
            x1s[rg][3][c]=fmaxf(areg[3]+Bm[(bI[3]*Nc+j3)*HD+c],0.f);
        }
        __syncthreads();
        float s0=0,s1=0,s2=0,s3=0;
        #pragma unroll 4
        for (int k=0;k<HD;k++){
            float w=w2s[k*HD+c];
            s0+=x1s[rg][0][k]*w; s1+=x1s[rg][1][k]*w;
            s2+=x1s[rg][2][k]*w; s3+=x1s[rg][3][k]*w;
        }
        acc0+=fmaxf(s0+b2c,0.f); acc1+=fmaxf(s1+b2c,0.f);
        acc2+=fmaxf(s2+b2c,0.f); acc3+=fmaxf(s3+b2c,0.f);
        __syncthreads();
    }
    /* layer 3 */
    x1s[rg][0][c]=acc0; x1s[rg][1][c]=acc1; x1s[rg][2][c]=acc2; x1s[rg][3][c]=acc3;
    __syncthreads();
    float o0,o1,o2,o3;
    o0=o1=o2=o3=20.0f*fb3[c];
    #pragma unroll 4
    for (int k=0;k<HD;k++){
        float w=fw3[k*HD+c];
        o0+=x1s[rg][0][k]*w; o1+=x1s[rg][1][k]*w;
        o2+=x1s[rg][2][k]*w; o3+=x1s[rg][3][k]*w;
    }
    M[(r0+0)*HD+c]=o0; M[(r0+1)*HD+c]=o1; M[(r0+2)*HD+c]=o2; M[(r0+3)*HD+c]=o3;
}

/* ---------------- kernel D: g-MLP + LSTM cell (in-place h,c update) ---------------- */
__global__ __launch_bounds__(192) void k_glstm(
    const float* __restrict__ X, const float* __restrict__ M,
    const float* __restrict__ gw1, const float* __restrict__ gb1,
    const float* __restrict__ gw2, const float* __restrict__ gb2,
    const float* __restrict__ gw3, const float* __restrict__ gb3,
    const float* __restrict__ wih, const float* __restrict__ whh,
    const float* __restrict__ bih, const float* __restrict__ bhh,
    float* __restrict__ H, float* __restrict__ C)
{
    __shared__ float xin[2][4][2*HD];
    __shared__ float hb[2][4][HD];
    __shared__ float t0[2][4][HD];
    __shared__ float t1[2][4][HD];
    const int tid=threadIdx.x; const int rg=tid/HD, c=tid-rg*HD;
    const int r0=blockIdx.x*8+rg*4;
    #pragma unroll
    for (int rr=0;rr<4;rr++){
        xin[rg][rr][c]    = X[(r0+rr)*HD+c];
        xin[rg][rr][HD+c] = M[(r0+rr)*HD+c];
        hb [rg][rr][c]    = H[(r0+rr)*HD+c];
    }
    __syncthreads();
    float s0,s1,s2,s3;
    /* g layer1, K=192 */
    s0=s1=s2=s3=gb1[c];
    #pragma unroll 4
    for (int k=0;k<2*HD;k++){
        float w=gw1[k*HD+c];
        s0+=xin[rg][0][k]*w; s1+=xin[rg][1][k]*w;
        s2+=xin[rg][2][k]*w; s3+=xin[rg][3][k]*w;
    }
    t0[rg][0][c]=fmaxf(s0,0.f); t0[rg][1][c]=fmaxf(s1,0.f);
    t0[rg][2][c]=fmaxf(s2,0.f); t0[rg][3][c]=fmaxf(s3,0.f);
    __syncthreads();
    /* g layer2 */
    s0=s1=s2=s3=gb2[c];
    #pragma unroll 4
    for (int k=0;k<HD;k++){
        float w=gw2[k*HD+c];
        s0+=t0[rg][0][k]*w; s1+=t0[rg][1][k]*w;
        s2+=t0[rg][2][k]*w; s3+=t0[rg][3][k]*w;
    }
    t1[rg][0][c]=fmaxf(s0,0.f); t1[rg][1][c]=fmaxf(s1,0.f);
    t1[rg][2][c]=fmaxf(s2,0.f); t1[rg][3][c]=fmaxf(s3,0.f);
    __syncthreads();
    /* g layer3 (linear) -> x_in, stored into xin[rg][rr][0..95] */
    s0=s1=s2=s3=gb3[c];
    #pragma unroll 4
    for (int k=0;k<HD;k++){
        float w=gw3[k*HD+c];
        s0+=t1[rg][0][k]*w; s1+=t1[rg][1][k]*w;
        s2+=t1[rg][2][k]*w; s3+=t1[rg][3][k]*w;
    }
    __syncthreads();   /* all reads of xin (layer1) are long done; reuse */
    xin[rg][0][c]=s0; xin[rg][1][c]=s1; xin[rg][2][c]=s2; xin[rg][3][c]=s3;
    __syncthreads();
    /* gates: q = 0:i 1:f 2:g 3:o */
    float g4[4][4];
    #pragma unroll
    for (int q=0;q<4;q++){
        float bb = bih[q*HD+c] + bhh[q*HD+c];
        float u0=bb,u1=bb,u2=bb,u3=bb;
        #pragma unroll 2
        for (int k=0;k<HD;k++){
            float wx=wih[k*4*HD + q*HD + c];
            float wh=whh[k*4*HD + q*HD + c];
            u0 += xin[rg][0][k]*wx + hb[rg][0][k]*wh;
            u1 += xin[rg][1][k]*wx + hb[rg][1][k]*wh;
            u2 += xin[rg][2][k]*wx + hb[rg][2][k]*wh;
            u3 += xin[rg][3][k]*wx + hb[rg][3][k]*wh;
        }
        g4[q][0]=u0; g4[q][1]=u1; g4[q][2]=u2; g4[q][3]=u3;
    }
    #pragma unroll
    for (int rr=0;rr<4;rr++){
        int idx=(r0+rr)*HD+c;
        float cold=C[idx];
        float iv=sigf(g4[0][rr]), fv=sigf(g4[1][rr]);
        float gv=tanhf(g4[2][rr]), ov=sigf(g4[3][rr]);
        float c2=fv*cold+iv*gv;
        float h2=ov*tanhf(c2);
        C[idx]=c2; H[idx]=h2;
    }
}

/* ---------------- kernel E: readout MLP -> d_out ---------------- */
__global__ __launch_bounds__(192) void k_rmlp(
    const float* __restrict__ H,
    const float* __restrict__ w1, const float* __restrict__ b1,
    const float* __restrict__ w2, const float* __restrict__ b2,
    const float* __restrict__ w3, const float* __restrict__ b3,
    float* __restrict__ out, int it)
{
    __shared__ float hb[2][4][HD];
    __shared__ float t0[2][4][HD];
    __shared__ float t1[2][4][HD];
    const int tid=threadIdx.x; const int rg=tid/HD, c=tid-rg*HD;
    const int r0=blockIdx.x*8+rg*4;
    #pragma unroll
    for (int rr=0;rr<4;rr++) hb[rg][rr][c]=H[(r0+rr)*HD+c];
    __syncthreads();
    float s0,s1,s2,s3;
    s0=s1=s2=s3=b1[c];
    #pragma unroll 4
    for (int k=0;k<HD;k++){
        float w=w1[k*HD+c];
        s0+=hb[rg][0][k]*w; s1+=hb[rg][1][k]*w;
        s2+=hb[rg][2][k]*w; s3+=hb[rg][3][k]*w;
    }
    t0[rg][0][c]=fmaxf(s0,0.f); t0[rg][1][c]=fmaxf(s1,0.f);
    t0[rg][2][c]=fmaxf(s2,0.f); t0[rg][3][c]=fmaxf(s3,0.f);
    __syncthreads();
    s0=s1=s2=s3=b2[c];
    #pragma unroll 4
    for (int k=0;k<HD;k++){
        float w=w2[k*HD+c];
        s0+=t0[rg][0][k]*w; s1+=t0[rg][1][k]*w;
        s2+=t0[rg][2][k]*w; s3+=t0[rg][3][k]*w;
    }
    t1[rg][0][c]=fmaxf(s0,0.f); t1[rg][1][c]=fmaxf(s1,0.f);
    t1[rg][2][c]=fmaxf(s2,0.f); t1[rg][3][c]=fmaxf(s3,0.f);
    __syncthreads();
    if (c < Edim){
        #pragma unroll
        for (int rr=0;rr<4;rr++){
            float o=b3[c];
            #pragma unroll 4
            for (int k=0;k<HD;k++) o += t1[rg][rr][k]*w3[k*Edim+c];
            out[((size_t)it*Rtot + (r0+rr))*Edim + c] = o;
        }
    }
}

extern "C" void kernel_launch(void* const* d_in, const int* in_sizes, int n_in,
                              void* d_out, int out_size, void* d_ws, size_t ws_size,
                              hipStream_t stream) {
    const int*   grids  = (const int*)  d_in[0];
    const int*   nbr    = (const int*)  d_in[1];
    /* d_in[2] = iters (always 4, compile-time NITER) */
    const float* c0     = (const float*)d_in[3];
    const float* embw   = (const float*)d_in[4];
    const float* in_w1  = (const float*)d_in[5];
    const float* in_b1  = (const float*)d_in[6];
    const float* in_w2  = (const float*)d_in[7];
    const float* in_b2  = (const float*)d_in[8];
    const float* in_w3  = (const float*)d_in[9];
    const float* in_b3  = (const float*)d_in[10];
    const float* f_w1   = (const float*)d_in[11];
    const float* f_b1   = (const float*)d_in[12];
    const float* f_w2   = (const float*)d_in[13];
    const float* f_b2   = (const float*)d_in[14];
    const float* f_w3   = (const float*)d_in[15];
    const float* f_b3   = (const float*)d_in[16];
    const float* g_w1   = (const float*)d_in[17];
    const float* g_b1   = (const float*)d_in[18];
    const float* g_w2   = (const float*)d_in[19];
    const float* g_b2   = (const float*)d_in[20];
    const float* g_w3   = (const float*)d_in[21];
    const float* g_b3   = (const float*)d_in[22];
    const float* wih    = (const float*)d_in[23];
    const float* whh    = (const float*)d_in[24];
    const float* bih    = (const float*)d_in[25];
    const float* bhh    = (const float*)d_in[26];
    const float* r_w1   = (const float*)d_in[27];
    const float* r_b1   = (const float*)d_in[28];
    const float* r_w2   = (const float*)d_in[29];
    const float* r_b2   = (const float*)d_in[30];
    const float* r_w3   = (const float*)d_in[31];
    const float* r_b3   = (const float*)d_in[32];

    float* ws = (float*)d_ws;
    float* X  = ws;
    float* H  = ws + (size_t)1*Rtot*HD;
    float* C  = ws + (size_t)2*Rtot*HD;
    float* Aa = ws + (size_t)3*Rtot*HD;
    float* Bm = ws + (size_t)4*Rtot*HD;
    float* Mm = ws + (size_t)5*Rtot*HD;
    float* out = (float*)d_out;

    dim3 blk(192), grd(Rtot/8);

    hipLaunchKernelGGL(k_embed, grd, blk, 0, stream,
        grids, embw, in_w1,in_b1,in_w2,in_b2,in_w3,in_b3, c0, X, H, C);

    for (int it=0; it<NITER; ++it){
        hipLaunchKernelGGL(k_ab,    grd, blk, 0, stream, H, f_w1, Aa, Bm);
        hipLaunchKernelGGL(k_edge,  grd, blk, 0, stream, Aa, Bm, nbr, f_b1, f_w2, f_b2, f_w3, f_b3, Mm);
        hipLaunchKernelGGL(k_glstm, grd, blk, 0, stream, X, Mm,
            g_w1,g_b1,g_w2,g_b2,g_w3,g_b3, wih,whh,bih,bhh, H, C);
        hipLaunchKernelGGL(k_rmlp,  grd, blk, 0, stream, H,
            r_w1,r_b1,r_w2,r_b2,r_w3,r_b3, out, it);
    }
}

// Round 2
// 2073.824 us; speedup vs baseline: 1.6463x; 1.6463x over previous
//
#include <hip/hip_runtime.h>
#include <math.h>

#define Bsz 512
#define Nc  81
#define Rtot (Bsz*Nc)     /* 41472 rows */
#define DEG 20
#define Edim 16
#define HD  96
#define NITER 4

typedef __attribute__((ext_vector_type(8))) __bf16 bf16x8;
typedef __attribute__((ext_vector_type(4))) float f32x4;

__device__ __forceinline__ float sigf(float x){ return 1.0f/(1.0f+expf(-x)); }

__device__ __forceinline__ unsigned short f2bf(float f){
    union{float f; unsigned u;} v; v.f=f;
    unsigned r = v.u + 0x7fff + ((v.u>>16)&1);
    return (unsigned short)(r>>16);
}
__device__ __forceinline__ float bf2f(unsigned short s){
    union{unsigned u; float f;} v; v.u=((unsigned)s)<<16; return v.f;
}
__device__ __forceinline__ bf16x8 pack8(const float* x){
    union{ unsigned short s[8]; bf16x8 b; } u;
    #pragma unroll
    for (int j=0;j<8;j++) u.s[j]=f2bf(x[j]);
    return u.b;
}
__device__ __forceinline__ bf16x8 pack8u(const unsigned short* x){
    union{ unsigned short s[8]; bf16x8 b; } u;
    #pragma unroll
    for (int j=0;j<8;j++) u.s[j]=x[j];
    return u.b;
}

/* ---------------- kernel A: embed + input MLP, init h,c ---------------- */
__global__ __launch_bounds__(192) void k_embed(
    const int* __restrict__ grids, const float* __restrict__ embw,
    const float* __restrict__ w1, const float* __restrict__ b1,
    const float* __restrict__ w2, const float* __restrict__ b2,
    const float* __restrict__ w3, const float* __restrict__ b3,
    const float* __restrict__ c0,
    float* __restrict__ X, float* __restrict__ H, float* __restrict__ C)
{
    __shared__ float e[2][4][Edim];
    __shared__ float a0[2][4][HD];
    __shared__ float a1[2][4][HD];
    const int tid = threadIdx.x;
    const int rg = tid / HD, c = tid - rg*HD;
    const int r0 = blockIdx.x*8 + rg*4;

    if (c < Edim) {
        #pragma unroll
        for (int rr=0;rr<4;rr++)
            e[rg][rr][c] = embw[grids[r0+rr]*Edim + c];
    }
    __syncthreads();
    float s0,s1,s2,s3;
    s0=s1=s2=s3=b1[c];
    #pragma unroll
    for (int k=0;k<Edim;k++){
        float w=w1[k*HD+c];
        s0+=e[rg][0][k]*w; s1+=e[rg][1][k]*w;
        s2+=e[rg][2][k]*w; s3+=e[rg][3][k]*w;
    }
    a0[rg][0][c]=fmaxf(s0,0.f); a0[rg][1][c]=fmaxf(s1,0.f);
    a0[rg][2][c]=fmaxf(s2,0.f); a0[rg][3][c]=fmaxf(s3,0.f);
    __syncthreads();
    s0=s1=s2=s3=b2[c];
    #pragma unroll 4
    for (int k=0;k<HD;k++){
        float w=w2[k*HD+c];
        s0+=a0[rg][0][k]*w; s1+=a0[rg][1][k]*w;
        s2+=a0[rg][2][k]*w; s3+=a0[rg][3][k]*w;
    }
    a1[rg][0][c]=fmaxf(s0,0.f); a1[rg][1][c]=fmaxf(s1,0.f);
    a1[rg][2][c]=fmaxf(s2,0.f); a1[rg][3][c]=fmaxf(s3,0.f);
    __syncthreads();
    s0=s1=s2=s3=b3[c];
    #pragma unroll 4
    for (int k=0;k<HD;k++){
        float w=w3[k*HD+c];
        s0+=a1[rg][0][k]*w; s1+=a1[rg][1][k]*w;
        s2+=a1[rg][2][k]*w; s3+=a1[rg][3][k]*w;
    }
    X[(r0+0)*HD+c]=s0; H[(r0+0)*HD+c]=s0; C[(r0+0)*HD+c]=c0[(r0+0)*HD+c];
    X[(r0+1)*HD+c]=s1; H[(r0+1)*HD+c]=s1; C[(r0+1)*HD+c]=c0[(r0+1)*HD+c];
    X[(r0+2)*HD+c]=s2; H[(r0+2)*HD+c]=s2; C[(r0+2)*HD+c]=c0[(r0+2)*HD+c];
    X[(r0+3)*HD+c]=s3; H[(r0+3)*HD+c]=s3; C[(r0+3)*HD+c]=c0[(r0+3)*HD+c];
}

/* ---------------- kernel B: A = h@fw1_top, Bm = h@fw1_bot ---------------- */
__global__ __launch_bounds__(192) void k_ab(
    const float* __restrict__ H, const float* __restrict__ fw1,
    float* __restrict__ A, float* __restrict__ Bm)
{
    __shared__ float hb[2][4][HD];
    const int tid=threadIdx.x; const int rg=tid/HD, c=tid-rg*HD;
    const int r0=blockIdx.x*8+rg*4;
    #pragma unroll
    for (int rr=0;rr<4;rr++) hb[rg][rr][c]=H[(r0+rr)*HD+c];
    __syncthreads();
    float a0=0,a1=0,a2=0,a3=0, q0=0,q1=0,q2=0,q3=0;
    #pragma unroll 4
    for (int k=0;k<HD;k++){
        float wt = fw1[k*HD+c];
        float wb = fw1[(HD+k)*HD+c];
        float h0=hb[rg][0][k], h1=hb[rg][1][k], h2=hb[rg][2][k], h3=hb[rg][3][k];
        a0+=h0*wt; a1+=h1*wt; a2+=h2*wt; a3+=h3*wt;
        q0+=h0*wb; q1+=h1*wb; q2+=h2*wb; q3+=h3*wb;
    }
    A [(r0+0)*HD+c]=a0; A [(r0+1)*HD+c]=a1; A [(r0+2)*HD+c]=a2; A [(r0+3)*HD+c]=a3;
    Bm[(r0+0)*HD+c]=q0; Bm[(r0+1)*HD+c]=q1; Bm[(r0+2)*HD+c]=q2; Bm[(r0+3)*HD+c]=q3;
}

/* ---------------- kernel C: edge message MLP via MFMA ----------------
   Per wave: 16 rows x 96 cols. W2 bf16 fragments in registers (18 frags).
   acc = sum_d relu( relu(A_i + b1 + Bm_j) @ W2 + b2 )   (fp32 accum)
   M   = acc @ W3 + 20*b3   via hi/lo bf16 split of acc (fp32-ish precision) */
__global__ __launch_bounds__(128) void k_edge_mfma(
    const float* __restrict__ A, const float* __restrict__ Bm,
    const int* __restrict__ nbr,
    const float* __restrict__ fb1, const float* __restrict__ fw2,
    const float* __restrict__ fb2, const float* __restrict__ fw3,
    const float* __restrict__ fb3,
    float* __restrict__ M)
{
    __shared__ float accs[2][16][104];   /* pad 96->104: write 4-way -> 2-way free */
    const int tid  = threadIdx.x;
    const int wave = tid>>6, lane = tid&63;
    const int row16 = lane&15, kgrp = lane>>4;
    const int rowA = blockIdx.x*32 + wave*16 + row16;
    const int bI = rowA/Nc, iI = rowA - bI*Nc;
    const float* BmB = Bm + (size_t)bI*Nc*HD;

    /* W2 fragments: B-layout, element (k=kf*32+kgrp*8+j, col=nf*16+row16) */
    bf16x8 w2f[3][6];
    #pragma unroll
    for (int kf=0; kf<3; kf++){
        #pragma unroll
        for (int nf=0; nf<6; nf++){
            float t[8];
            #pragma unroll
            for (int j=0;j<8;j++)
                t[j] = fw2[(kf*32+kgrp*8+j)*HD + nf*16+row16];
            w2f[kf][nf] = pack8(t);
        }
    }

    /* A row slice + b1, fp32, reused across all 20 edges */
    float a[3][8];
    #pragma unroll
    for (int kf=0;kf<3;kf++){
        const float4* Ar = (const float4*)(A + (size_t)rowA*HD + kf*32 + kgrp*8);
        const float4* Br = (const float4*)(fb1 + kf*32 + kgrp*8);
        float4 p=Ar[0], q=Ar[1], bp=Br[0], bq=Br[1];
        a[kf][0]=p.x+bp.x; a[kf][1]=p.y+bp.y; a[kf][2]=p.z+bp.z; a[kf][3]=p.w+bp.w;
        a[kf][4]=q.x+bq.x; a[kf][5]=q.y+bq.y; a[kf][6]=q.z+bq.z; a[kf][7]=q.w+bq.w;
    }
    float b2c[6], b3c[6];
    #pragma unroll
    for (int nf=0;nf<6;nf++){ b2c[nf]=fb2[nf*16+row16]; b3c[nf]=20.0f*fb3[nf*16+row16]; }

    f32x4 acc[6];
    #pragma unroll
    for (int nf=0;nf<6;nf++) acc[nf]=(f32x4){0.f,0.f,0.f,0.f};

    const int* nrow = nbr + iI*DEG;
    #pragma unroll 2
    for (int d=0; d<DEG; d++){
        int j = nrow[d];
        const float* Vb = BmB + (size_t)j*HD + kgrp*8;
        bf16x8 xf[3];
        #pragma unroll
        for (int kf=0;kf<3;kf++){
            const float4* Vr = (const float4*)(Vb + kf*32);
            float4 p=Vr[0], q=Vr[1];
            float t[8]={p.x,p.y,p.z,p.w,q.x,q.y,q.z,q.w};
            #pragma unroll
            for (int jj=0;jj<8;jj++) t[jj]=fmaxf(a[kf][jj]+t[jj],0.f);
            xf[kf]=pack8(t);
        }
        f32x4 c[6];
        #pragma unroll
        for (int nf=0;nf<6;nf++) c[nf]=(f32x4){0.f,0.f,0.f,0.f};
        #pragma unroll
        for (int kf=0;kf<3;kf++){
            #pragma unroll
            for (int nf=0;nf<6;nf++)
                c[nf]=__builtin_amdgcn_mfma_f32_16x16x32_bf16(xf[kf],w2f[kf][nf],c[nf],0,0,0);
        }
        #pragma unroll
        for (int nf=0;nf<6;nf++){
            #pragma unroll
            for (int q2=0;q2<4;q2++)
                acc[nf][q2]+=fmaxf(c[nf][q2]+b2c[nf],0.f);
        }
    }

    /* layer 3: transpose acc (C-layout) -> A-layout via LDS, hi/lo bf16 MFMA */
    #pragma unroll
    for (int nf=0;nf<6;nf++){
        #pragma unroll
        for (int q2=0;q2<4;q2++)
            accs[wave][kgrp*4+q2][nf*16+row16]=acc[nf][q2];
    }
    __syncthreads();

    f32x4 c2[6];
    #pragma unroll
    for (int nf=0;nf<6;nf++) c2[nf]=(f32x4){0.f,0.f,0.f,0.f};
    #pragma unroll
    for (int kf=0;kf<3;kf++){
        const float* rp=&accs[wave][row16][kf*32+kgrp*8];
        float h[8], lo[8]; unsigned short hb[8];
        #pragma unroll
        for (int j=0;j<8;j++){ h[j]=rp[j]; hb[j]=f2bf(h[j]); lo[j]=h[j]-bf2f(hb[j]); }
        bf16x8 hif=pack8u(hb), lof=pack8(lo);
        #pragma unroll
        for (int nf=0;nf<6;nf++){
            float t[8];
            #pragma unroll
            for (int j=0;j<8;j++)
                t[j]=fw3[(kf*32+kgrp*8+j)*HD + nf*16+row16];
            bf16x8 w3f=pack8(t);
            c2[nf]=__builtin_amdgcn_mfma_f32_16x16x32_bf16(hif,w3f,c2[nf],0,0,0);
            c2[nf]=__builtin_amdgcn_mfma_f32_16x16x32_bf16(lof,w3f,c2[nf],0,0,0);
        }
    }
    const int rowOut = blockIdx.x*32 + wave*16 + kgrp*4;
    #pragma unroll
    for (int nf=0;nf<6;nf++){
        #pragma unroll
        for (int q2=0;q2<4;q2++)
            M[(size_t)(rowOut+q2)*HD + nf*16+row16] = c2[nf][q2]+b3c[nf];
    }
}

/* ---------------- kernel D: g-MLP + LSTM cell ---------------- */
__global__ __launch_bounds__(192) void k_glstm(
    const float* __restrict__ X, const float* __restrict__ M,
    const float* __restrict__ gw1, const float* __restrict__ gb1,
    const float* __restrict__ gw2, const float* __restrict__ gb2,
    const float* __restrict__ gw3, const float* __restrict__ gb3,
    const float* __restrict__ wih, const float* __restrict__ whh,
    const float* __restrict__ bih, const float* __restrict__ bhh,
    float* __restrict__ H, float* __restrict__ C)
{
    __shared__ float xin[2][4][2*HD];
    __shared__ float hb[2][4][HD];
    __shared__ float t0[2][4][HD];
    __shared__ float t1[2][4][HD];
    const int tid=threadIdx.x; const int rg=tid/HD, c=tid-rg*HD;
    const int r0=blockIdx.x*8+rg*4;
    #pragma unroll
    for (int rr=0;rr<4;rr++){
        xin[rg][rr][c]    = X[(r0+rr)*HD+c];
        xin[rg][rr][HD+c] = M[(r0+rr)*HD+c];
        hb [rg][rr][c]    = H[(r0+rr)*HD+c];
    }
    __syncthreads();
    float s0,s1,s2,s3;
    s0=s1=s2=s3=gb1[c];
    #pragma unroll 4
    for (int k=0;k<2*HD;k++){
        float w=gw1[k*HD+c];
        s0+=xin[rg][0][k]*w; s1+=xin[rg][1][k]*w;
        s2+=xin[rg][2][k]*w; s3+=xin[rg][3][k]*w;
    }
    t0[rg][0][c]=fmaxf(s0,0.f); t0[rg][1][c]=fmaxf(s1,0.f);
    t0[rg][2][c]=fmaxf(s2,0.f); t0[rg][3][c]=fmaxf(s3,0.f);
    __syncthreads();
    s0=s1=s2=s3=gb2[c];
    #pragma unroll 4
    for (int k=0;k<HD;k++){
        float w=gw2[k*HD+c];
        s0+=t0[rg][0][k]*w; s1+=t0[rg][1][k]*w;
        s2+=t0[rg][2][k]*w; s3+=t0[rg][3][k]*w;
    }
    t1[rg][0][c]=fmaxf(s0,0.f); t1[rg][1][c]=fmaxf(s1,0.f);
    t1[rg][2][c]=fmaxf(s2,0.f); t1[rg][3][c]=fmaxf(s3,0.f);
    __syncthreads();
    s0=s1=s2=s3=gb3[c];
    #pragma unroll 4
    for (int k=0;k<HD;k++){
        float w=gw3[k*HD+c];
        s0+=t1[rg][0][k]*w; s1+=t1[rg][1][k]*w;
        s2+=t1[rg][2][k]*w; s3+=t1[rg][3][k]*w;
    }
    __syncthreads();
    xin[rg][0][c]=s0; xin[rg][1][c]=s1; xin[rg][2][c]=s2; xin[rg][3][c]=s3;
    __syncthreads();
    float g4[4][4];
    #pragma unroll
    for (int q=0;q<4;q++){
        float bb = bih[q*HD+c] + bhh[q*HD+c];
        float u0=bb,u1=bb,u2=bb,u3=bb;
        #pragma unroll 2
        for (int k=0;k<HD;k++){
            float wx=wih[k*4*HD + q*HD + c];
            float wh=whh[k*4*HD + q*HD + c];
            u0 += xin[rg][0][k]*wx + hb[rg][0][k]*wh;
            u1 += xin[rg][1][k]*wx + hb[rg][1][k]*wh;
            u2 += xin[rg][2][k]*wx + hb[rg][2][k]*wh;
            u3 += xin[rg][3][k]*wx + hb[rg][3][k]*wh;
        }
        g4[q][0]=u0; g4[q][1]=u1; g4[q][2]=u2; g4[q][3]=u3;
    }
    #pragma unroll
    for (int rr=0;rr<4;rr++){
        int idx=(r0+rr)*HD+c;
        float cold=C[idx];
        float iv=sigf(g4[0][rr]), fv=sigf(g4[1][rr]);
        float gv=tanhf(g4[2][rr]), ov=sigf(g4[3][rr]);
        float c2=fv*cold+iv*gv;
        float h2=ov*tanhf(c2);
        C[idx]=c2; H[idx]=h2;
    }
}

/* ---------------- kernel E: readout MLP -> d_out ---------------- */
__global__ __launch_bounds__(192) void k_rmlp(
    const float* __restrict__ H,
    const float* __restrict__ w1, const float* __restrict__ b1,
    const float* __restrict__ w2, const float* __restrict__ b2,
    const float* __restrict__ w3, const float* __restrict__ b3,
    float* __restrict__ out, int it)
{
    __shared__ float hb[2][4][HD];
    __shared__ float t0[2][4][HD];
    __shared__ float t1[2][4][HD];
    const int tid=threadIdx.x; const int rg=tid/HD, c=tid-rg*HD;
    const int r0=blockIdx.x*8+rg*4;
    #pragma unroll
    for (int rr=0;rr<4;rr++) hb[rg][rr][c]=H[(r0+rr)*HD+c];
    __syncthreads();
    float s0,s1,s2,s3;
    s0=s1=s2=s3=b1[c];
    #pragma unroll 4
    for (int k=0;k<HD;k++){
        float w=w1[k*HD+c];
        s0+=hb[rg][0][k]*w; s1+=hb[rg][1][k]*w;
        s2+=hb[rg][2][k]*w; s3+=hb[rg][3][k]*w;
    }
    t0[rg][0][c]=fmaxf(s0,0.f); t0[rg][1][c]=fmaxf(s1,0.f);
    t0[rg][2][c]=fmaxf(s2,0.f); t0[rg][3][c]=fmaxf(s3,0.f);
    __syncthreads();
    s0=s1=s2=s3=b2[c];
    #pragma unroll 4
    for (int k=0;k<HD;k++){
        float w=w2[k*HD+c];
        s0+=t0[rg][0][k]*w; s1+=t0[rg][1][k]*w;
        s2+=t0[rg][2][k]*w; s3+=t0[rg][3][k]*w;
    }
    t1[rg][0][c]=fmaxf(s0,0.f); t1[rg][1][c]=fmaxf(s1,0.f);
    t1[rg][2][c]=fmaxf(s2,0.f); t1[rg][3][c]=fmaxf(s3,0.f);
    __syncthreads();
    if (c < Edim){
        #pragma unroll
        for (int rr=0;rr<4;rr++){
            float o=b3[c];
            #pragma unroll 4
            for (int k=0;k<HD;k++) o += t1[rg][rr][k]*w3[k*Edim+c];
            out[((size_t)it*Rtot + (r0+rr))*Edim + c] = o;
        }
    }
}

extern "C" void kernel_launch(void* const* d_in, const int* in_sizes, int n_in,
                              void* d_out, int out_size, void* d_ws, size_t ws_size,
                              hipStream_t stream) {
    const int*   grids  = (const int*)  d_in[0];
    const int*   nbr    = (const int*)  d_in[1];
    const float* c0     = (const float*)d_in[3];
    const float* embw   = (const float*)d_in[4];
    const float* in_w1  = (const float*)d_in[5];
    const float* in_b1  = (const float*)d_in[6];
    const float* in_w2  = (const float*)d_in[7];
    const float* in_b2  = (const float*)d_in[8];
    const float* in_w3  = (const float*)d_in[9];
    const float* in_b3  = (const float*)d_in[10];
    const float* f_w1   = (const float*)d_in[11];
    const float* f_b1   = (const float*)d_in[12];
    const float* f_w2   = (const float*)d_in[13];
    const float* f_b2   = (const float*)d_in[14];
    const float* f_w3   = (const float*)d_in[15];
    const float* f_b3   = (const float*)d_in[16];
    const float* g_w1   = (const float*)d_in[17];
    const float* g_b1   = (const float*)d_in[18];
    const float* g_w2   = (const float*)d_in[19];
    const float* g_b2   = (const float*)d_in[20];
    const float* g_w3   = (const float*)d_in[21];
    const float* g_b3   = (const float*)d_in[22];
    const float* wih    = (const float*)d_in[23];
    const float* whh    = (const float*)d_in[24];
    const float* bih    = (const float*)d_in[25];
    const float* bhh    = (const float*)d_in[26];
    const float* r_w1   = (const float*)d_in[27];
    const float* r_b1   = (const float*)d_in[28];
    const float* r_w2   = (const float*)d_in[29];
    const float* r_b2   = (const float*)d_in[30];
    const float* r_w3   = (const float*)d_in[31];
    const float* r_b3   = (const float*)d_in[32];

    float* ws = (float*)d_ws;
    float* X  = ws;
    float* H  = ws + (size_t)1*Rtot*HD;
    float* C  = ws + (size_t)2*Rtot*HD;
    float* Aa = ws + (size_t)3*Rtot*HD;
    float* Bm = ws + (size_t)4*Rtot*HD;
    float* Mm = ws + (size_t)5*Rtot*HD;
    float* out = (float*)d_out;

    dim3 blk(192), grd(Rtot/8);

    hipLaunchKernelGGL(k_embed, grd, blk, 0, stream,
        grids, embw, in_w1,in_b1,in_w2,in_b2,in_w3,in_b3, c0, X, H, C);

    for (int it=0; it<NITER; ++it){
        hipLaunchKernelGGL(k_ab, grd, blk, 0, stream, H, f_w1, Aa, Bm);
        hipLaunchKernelGGL(k_edge_mfma, dim3(Rtot/32), dim3(128), 0, stream,
            Aa, Bm, nbr, f_b1, f_w2, f_b2, f_w3, f_b3, Mm);
        hipLaunchKernelGGL(k_glstm, grd, blk, 0, stream, X, Mm,
            g_w1,g_b1,g_w2,g_b2,g_w3,g_b3, wih,whh,bih,bhh, H, C);
        hipLaunchKernelGGL(k_rmlp, grd, blk, 0, stream, H,
            r_w1,r_b1,r_w2,r_b2,r_w3,r_b3, out, it);
    }
}

// Round 3
// 622.744 us; speedup vs baseline: 5.4825x; 3.3301x over previous
//
#include <hip/hip_runtime.h>
#include <math.h>

#define Bsz 512
#define Nc  81
#define Rtot (Bsz*Nc)     /* 41472 rows */
#define DEG 20
#define Edim 16
#define HD  96
#define NITER 4

typedef __attribute__((ext_vector_type(8))) __bf16 bf16x8;
typedef __attribute__((ext_vector_type(4))) float f32x4;

__device__ __forceinline__ float sigf(float x){ return 1.0f/(1.0f+__expf(-x)); }
__device__ __forceinline__ float tanh_fast(float x){ return 2.0f/(1.0f+__expf(-2.0f*x)) - 1.0f; }

__device__ __forceinline__ unsigned short f2bf(float f){
    union{float f; unsigned u;} v; v.f=f;
    unsigned r = v.u + 0x7fff + ((v.u>>16)&1);
    return (unsigned short)(r>>16);
}
__device__ __forceinline__ float bf2f(unsigned short s){
    union{unsigned u; float f;} v; v.u=((unsigned)s)<<16; return v.f;
}
__device__ __forceinline__ bf16x8 pack8f(const float* x){
    bf16x8 r;
    #pragma unroll
    for (int j=0;j<8;j++) r[j]=(__bf16)x[j];
    return r;
}
__device__ __forceinline__ bf16x8 packrow(const float* p){
    const float4 a=((const float4*)p)[0], b=((const float4*)p)[1];
    bf16x8 r;
    r[0]=(__bf16)a.x; r[1]=(__bf16)a.y; r[2]=(__bf16)a.z; r[3]=(__bf16)a.w;
    r[4]=(__bf16)b.x; r[5]=(__bf16)b.y; r[6]=(__bf16)b.z; r[7]=(__bf16)b.w;
    return r;
}
__device__ __forceinline__ bf16x8 ldw(const __bf16* p){ return *(const bf16x8*)p; }

/* bf16 transposed-weight offsets inside ws (elements) */
#define OFF_FW1T 0          /* [192][96] */
#define OFF_FW2T 18432      /* [96][96]  */
#define OFF_FW3T 27648      /* [96][96]  */
#define OFF_GW1T 36864      /* [96][192] */
#define OFF_GW2T 55296      /* [96][96]  */
#define OFF_GW3T 64512      /* [96][96]  */
#define OFF_WIHT 73728      /* [384][96] */
#define OFF_WHHT 110592     /* [384][96] */
#define OFF_RW1T 147456     /* [96][96]  */
#define OFF_RW2T 156672     /* [96][96]  */
#define OFF_RW3T 165888     /* [16][96]  */
#define WT_TOTAL 167424

/* ---------------- k_prep: one-time bf16 transposed weight conversion ---------------- */
__global__ __launch_bounds__(256) void k_prep(
    const float* __restrict__ fw1, const float* __restrict__ fw2, const float* __restrict__ fw3,
    const float* __restrict__ gw1, const float* __restrict__ gw2, const float* __restrict__ gw3,
    const float* __restrict__ wih, const float* __restrict__ whh,
    const float* __restrict__ rw1, const float* __restrict__ rw2, const float* __restrict__ rw3,
    __bf16* __restrict__ wt)
{
    int i = blockIdx.x*256 + threadIdx.x;
    if (i >= WT_TOTAL) return;
    int j = i;
    if (j < 18432){ int n=j/96, k=j-n*96;
        wt[OFF_FW1T+j] = (__bf16)(n<96 ? fw1[k*96+n] : fw1[(96+k)*96+(n-96)]); return; }
    j -= 18432;
    if (j < 9216){ int n=j/96, k=j-n*96; wt[OFF_FW2T+j]=(__bf16)fw2[k*96+n]; return; }
    j -= 9216;
    if (j < 9216){ int n=j/96, k=j-n*96; wt[OFF_FW3T+j]=(__bf16)fw3[k*96+n]; return; }
    j -= 9216;
    if (j < 18432){ int n=j/192, k=j-n*192; wt[OFF_GW1T+j]=(__bf16)gw1[k*96+n]; return; }
    j -= 18432;
    if (j < 9216){ int n=j/96, k=j-n*96; wt[OFF_GW2T+j]=(__bf16)gw2[k*96+n]; return; }
    j -= 9216;
    if (j < 9216){ int n=j/96, k=j-n*96; wt[OFF_GW3T+j]=(__bf16)gw3[k*96+n]; return; }
    j -= 9216;
    if (j < 36864){ int n=j/96, k=j-n*96; wt[OFF_WIHT+j]=(__bf16)wih[k*384+n]; return; }
    j -= 36864;
    if (j < 36864){ int n=j/96, k=j-n*96; wt[OFF_WHHT+j]=(__bf16)whh[k*384+n]; return; }
    j -= 36864;
    if (j < 9216){ int n=j/96, k=j-n*96; wt[OFF_RW1T+j]=(__bf16)rw1[k*96+n]; return; }
    j -= 9216;
    if (j < 9216){ int n=j/96, k=j-n*96; wt[OFF_RW2T+j]=(__bf16)rw2[k*96+n]; return; }
    j -= 9216;
    { int n=j/96, k=j-n*96; wt[OFF_RW3T+j]=(__bf16)rw3[k*16+n]; }
}

/* ---------------- kernel A: embed + input MLP, init h,c (fp32, runs once) ---------------- */
__global__ __launch_bounds__(192) void k_embed(
    const int* __restrict__ grids, const float* __restrict__ embw,
    const float* __restrict__ w1, const float* __restrict__ b1,
    const float* __restrict__ w2, const float* __restrict__ b2,
    const float* __restrict__ w3, const float* __restrict__ b3,
    const float* __restrict__ c0,
    float* __restrict__ X, float* __restrict__ H, float* __restrict__ C)
{
    __shared__ float e[2][4][Edim];
    __shared__ float a0[2][4][HD];
    __shared__ float a1[2][4][HD];
    const int tid = threadIdx.x;
    const int rg = tid / HD, c = tid - rg*HD;
    const int r0 = blockIdx.x*8 + rg*4;

    if (c < Edim) {
        #pragma unroll
        for (int rr=0;rr<4;rr++)
            e[rg][rr][c] = embw[grids[r0+rr]*Edim + c];
    }
    __syncthreads();
    float s0,s1,s2,s3;
    s0=s1=s2=s3=b1[c];
    #pragma unroll
    for (int k=0;k<Edim;k++){
        float w=w1[k*HD+c];
        s0+=e[rg][0][k]*w; s1+=e[rg][1][k]*w;
        s2+=e[rg][2][k]*w; s3+=e[rg][3][k]*w;
    }
    a0[rg][0][c]=fmaxf(s0,0.f); a0[rg][1][c]=fmaxf(s1,0.f);
    a0[rg][2][c]=fmaxf(s2,0.f); a0[rg][3][c]=fmaxf(s3,0.f);
    __syncthreads();
    s0=s1=s2=s3=b2[c];
    #pragma unroll 4
    for (int k=0;k<HD;k++){
        float w=w2[k*HD+c];
        s0+=a0[rg][0][k]*w; s1+=a0[rg][1][k]*w;
        s2+=a0[rg][2][k]*w; s3+=a0[rg][3][k]*w;
    }
    a1[rg][0][c]=fmaxf(s0,0.f); a1[rg][1][c]=fmaxf(s1,0.f);
    a1[rg][2][c]=fmaxf(s2,0.f); a1[rg][3][c]=fmaxf(s3,0.f);
    __syncthreads();
    s0=s1=s2=s3=b3[c];
    #pragma unroll 4
    for (int k=0;k<HD;k++){
        float w=w3[k*HD+c];
        s0+=a1[rg][0][k]*w; s1+=a1[rg][1][k]*w;
        s2+=a1[rg][2][k]*w; s3+=a1[rg][3][k]*w;
    }
    X[(r0+0)*HD+c]=s0; H[(r0+0)*HD+c]=s0; C[(r0+0)*HD+c]=c0[(r0+0)*HD+c];
    X[(r0+1)*HD+c]=s1; H[(r0+1)*HD+c]=s1; C[(r0+1)*HD+c]=c0[(r0+1)*HD+c];
    X[(r0+2)*HD+c]=s2; H[(r0+2)*HD+c]=s2; C[(r0+2)*HD+c]=c0[(r0+2)*HD+c];
    X[(r0+3)*HD+c]=s3; H[(r0+3)*HD+c]=s3; C[(r0+3)*HD+c]=c0[(r0+3)*HD+c];
}

/* ---------------- k_ab_mfma: [A|Bm] = h @ fw1 ---------------- */
__global__ __launch_bounds__(128) void k_ab_mfma(
    const float* __restrict__ H, const __bf16* __restrict__ fw1t,
    float* __restrict__ A, float* __restrict__ Bm)
{
    const int tid=threadIdx.x, wave=tid>>6, lane=tid&63;
    const int row16=lane&15, kgrp=lane>>4;
    const int rowA=blockIdx.x*32+wave*16+row16;
    const int rowO=blockIdx.x*32+wave*16+kgrp*4;
    bf16x8 hf[3];
    #pragma unroll
    for (int kf=0;kf<3;kf++) hf[kf]=packrow(H+(size_t)rowA*HD+kf*32+kgrp*8);
    #pragma unroll
    for (int nf=0;nf<12;nf++){
        f32x4 c={0.f,0.f,0.f,0.f};
        #pragma unroll
        for (int kf=0;kf<3;kf++)
            c=__builtin_amdgcn_mfma_f32_16x16x32_bf16(hf[kf], ldw(fw1t+(size_t)(nf*16+row16)*HD+kf*32+kgrp*8), c, 0,0,0);
        float* dst = (nf<6)? A : Bm;
        int col = ((nf<6)? nf : nf-6)*16 + row16;
        #pragma unroll
        for (int q=0;q<4;q++) dst[(size_t)(rowO+q)*HD+col]=c[q];
    }
}

/* ---------------- k_edge_mfma: edge message MLP ---------------- */
__global__ __launch_bounds__(128) void k_edge_mfma(
    const float* __restrict__ A, const float* __restrict__ Bm,
    const int* __restrict__ nbr,
    const float* __restrict__ fb1, const __bf16* __restrict__ fw2t,
    const float* __restrict__ fb2, const __bf16* __restrict__ fw3t,
    const float* __restrict__ fb3,
    float* __restrict__ M)
{
    __shared__ float accs[2][16][104];
    const int tid  = threadIdx.x;
    const int wave = tid>>6, lane = tid&63;
    const int row16 = lane&15, kgrp = lane>>4;
    const int rowA = blockIdx.x*32 + wave*16 + row16;
    const int bI = rowA/Nc, iI = rowA - bI*Nc;
    const float* BmB = Bm + (size_t)bI*Nc*HD;

    bf16x8 w2f[3][6];
    #pragma unroll
    for (int kf=0; kf<3; kf++)
        #pragma unroll
        for (int nf=0; nf<6; nf++)
            w2f[kf][nf] = ldw(fw2t + (size_t)(nf*16+row16)*HD + kf*32+kgrp*8);

    float a[3][8];
    #pragma unroll
    for (int kf=0;kf<3;kf++){
        const float4* Ar = (const float4*)(A + (size_t)rowA*HD + kf*32 + kgrp*8);
        const float4* Br = (const float4*)(fb1 + kf*32 + kgrp*8);
        float4 p=Ar[0], q=Ar[1], bp=Br[0], bq=Br[1];
        a[kf][0]=p.x+bp.x; a[kf][1]=p.y+bp.y; a[kf][2]=p.z+bp.z; a[kf][3]=p.w+bp.w;
        a[kf][4]=q.x+bq.x; a[kf][5]=q.y+bq.y; a[kf][6]=q.z+bq.z; a[kf][7]=q.w+bq.w;
    }
    float b2c[6], b3c[6];
    #pragma unroll
    for (int nf=0;nf<6;nf++){ b2c[nf]=fb2[nf*16+row16]; b3c[nf]=20.0f*fb3[nf*16+row16]; }

    f32x4 acc[6];
    #pragma unroll
    for (int nf=0;nf<6;nf++) acc[nf]=(f32x4){0.f,0.f,0.f,0.f};

    const int* nrow = nbr + iI*DEG;
    #pragma unroll 2
    for (int d=0; d<DEG; d++){
        int j = nrow[d];
        const float* Vb = BmB + (size_t)j*HD + kgrp*8;
        bf16x8 xf[3];
        #pragma unroll
        for (int kf=0;kf<3;kf++){
            const float4* Vr = (const float4*)(Vb + kf*32);
            float4 p=Vr[0], q=Vr[1];
            float t[8]={p.x,p.y,p.z,p.w,q.x,q.y,q.z,q.w};
            #pragma unroll
            for (int jj=0;jj<8;jj++) t[jj]=fmaxf(a[kf][jj]+t[jj],0.f);
            xf[kf]=pack8f(t);
        }
        f32x4 c[6];
        #pragma unroll
        for (int nf=0;nf<6;nf++) c[nf]=(f32x4){0.f,0.f,0.f,0.f};
        #pragma unroll
        for (int kf=0;kf<3;kf++)
            #pragma unroll
            for (int nf=0;nf<6;nf++)
                c[nf]=__builtin_amdgcn_mfma_f32_16x16x32_bf16(xf[kf],w2f[kf][nf],c[nf],0,0,0);
        #pragma unroll
        for (int nf=0;nf<6;nf++)
            #pragma unroll
            for (int q2=0;q2<4;q2++)
                acc[nf][q2]+=fmaxf(c[nf][q2]+b2c[nf],0.f);
    }

    /* layer 3: transpose acc -> A-layout via LDS, hi/lo bf16 MFMA */
    #pragma unroll
    for (int nf=0;nf<6;nf++)
        #pragma unroll
        for (int q2=0;q2<4;q2++)
            accs[wave][kgrp*4+q2][nf*16+row16]=acc[nf][q2];
    __syncthreads();

    f32x4 c2[6];
    #pragma unroll
    for (int nf=0;nf<6;nf++) c2[nf]=(f32x4){0.f,0.f,0.f,0.f};
    #pragma unroll
    for (int kf=0;kf<3;kf++){
        const float* rp=&accs[wave][row16][kf*32+kgrp*8];
        float h[8], lo[8]; unsigned short hb[8];
        #pragma unroll
        for (int j=0;j<8;j++){ h[j]=rp[j]; hb[j]=f2bf(h[j]); lo[j]=h[j]-bf2f(hb[j]); }
        bf16x8 hif, lof;
        #pragma unroll
        for (int j=0;j<8;j++){ union{unsigned short s; __bf16 b;} u; u.s=hb[j]; hif[j]=u.b; lof[j]=(__bf16)lo[j]; }
        #pragma unroll
        for (int nf=0;nf<6;nf++){
            bf16x8 w3f = ldw(fw3t + (size_t)(nf*16+row16)*HD + kf*32+kgrp*8);
            c2[nf]=__builtin_amdgcn_mfma_f32_16x16x32_bf16(hif,w3f,c2[nf],0,0,0);
            c2[nf]=__builtin_amdgcn_mfma_f32_16x16x32_bf16(lof,w3f,c2[nf],0,0,0);
        }
    }
    const int rowOut = blockIdx.x*32 + wave*16 + kgrp*4;
    #pragma unroll
    for (int nf=0;nf<6;nf++)
        #pragma unroll
        for (int q2=0;q2<4;q2++)
            M[(size_t)(rowOut+q2)*HD + nf*16+row16] = c2[nf][q2]+b3c[nf];
}

/* ---------------- k_glstm_fused: g-MLP + LSTM + readout MLP, all MFMA ---------------- */
__global__ __launch_bounds__(128) void k_glstm_fused(
    const float* __restrict__ X, const float* __restrict__ M,
    float* __restrict__ H, float* __restrict__ C,
    const __bf16* __restrict__ gw1t, const float* __restrict__ gb1,
    const __bf16* __restrict__ gw2t, const float* __restrict__ gb2,
    const __bf16* __restrict__ gw3t, const float* __restrict__ gb3,
    const __bf16* __restrict__ wiht, const __bf16* __restrict__ whht,
    const float* __restrict__ bih, const float* __restrict__ bhh,
    const __bf16* __restrict__ rw1t, const float* __restrict__ rb1,
    const __bf16* __restrict__ rw2t, const float* __restrict__ rb2,
    const __bf16* __restrict__ rw3t, const float* __restrict__ rb3,
    float* __restrict__ out, int it)
{
    __shared__ float tr[2][16][104];
    const int tid=threadIdx.x, wave=tid>>6, lane=tid&63;
    const int row16=lane&15, kgrp=lane>>4;
    const int rowA = blockIdx.x*32 + wave*16 + row16;
    const int rowO = blockIdx.x*32 + wave*16 + kgrp*4;
    const int ko = kgrp*8;

    /* ---- g-MLP layer 1: concat(X,M) @ gw1 ---- */
    bf16x8 xm[6];
    #pragma unroll
    for (int kf=0;kf<3;kf++) xm[kf]   = packrow(X + (size_t)rowA*HD + kf*32 + ko);
    #pragma unroll
    for (int kf=0;kf<3;kf++) xm[3+kf] = packrow(M + (size_t)rowA*HD + kf*32 + ko);
    #pragma unroll
    for (int nf=0;nf<6;nf++){
        f32x4 c={0.f,0.f,0.f,0.f};
        #pragma unroll
        for (int kf=0;kf<6;kf++)
            c=__builtin_amdgcn_mfma_f32_16x16x32_bf16(xm[kf], ldw(gw1t+(size_t)(nf*16+row16)*192+kf*32+ko), c,0,0,0);
        float b=gb1[nf*16+row16];
        #pragma unroll
        for (int q=0;q<4;q++) tr[wave][kgrp*4+q][nf*16+row16]=fmaxf(c[q]+b,0.f);
    }
    __syncthreads();
    bf16x8 t[3];
    #pragma unroll
    for (int kf=0;kf<3;kf++) t[kf]=pack8f(&tr[wave][row16][kf*32+ko]);
    __syncthreads();
    /* ---- layer 2 ---- */
    #pragma unroll
    for (int nf=0;nf<6;nf++){
        f32x4 c={0.f,0.f,0.f,0.f};
        #pragma unroll
        for (int kf=0;kf<3;kf++)
            c=__builtin_amdgcn_mfma_f32_16x16x32_bf16(t[kf], ldw(gw2t+(size_t)(nf*16+row16)*HD+kf*32+ko), c,0,0,0);
        float b=gb2[nf*16+row16];
        #pragma unroll
        for (int q=0;q<4;q++) tr[wave][kgrp*4+q][nf*16+row16]=fmaxf(c[q]+b,0.f);
    }
    __syncthreads();
    #pragma unroll
    for (int kf=0;kf<3;kf++) t[kf]=pack8f(&tr[wave][row16][kf*32+ko]);
    __syncthreads();
    /* ---- layer 3 (linear) -> x_in ---- */
    #pragma unroll
    for (int nf=0;nf<6;nf++){
        f32x4 c={0.f,0.f,0.f,0.f};
        #pragma unroll
        for (int kf=0;kf<3;kf++)
            c=__builtin_amdgcn_mfma_f32_16x16x32_bf16(t[kf], ldw(gw3t+(size_t)(nf*16+row16)*HD+kf*32+ko), c,0,0,0);
        float b=gb3[nf*16+row16];
        #pragma unroll
        for (int q=0;q<4;q++) tr[wave][kgrp*4+q][nf*16+row16]=c[q]+b;
    }
    __syncthreads();
    bf16x8 xinf[3];
    #pragma unroll
    for (int kf=0;kf<3;kf++) xinf[kf]=pack8f(&tr[wave][row16][kf*32+ko]);
    __syncthreads();

    /* ---- LSTM gates ---- */
    bf16x8 hf[3];
    #pragma unroll
    for (int kf=0;kf<3;kf++) hf[kf]=packrow(H + (size_t)rowA*HD + kf*32 + ko);

    #pragma unroll 2
    for (int nf=0;nf<6;nf++){
        const int col = nf*16+row16;
        f32x4 ci={0.f,0.f,0.f,0.f}, cf={0.f,0.f,0.f,0.f}, cg={0.f,0.f,0.f,0.f}, co={0.f,0.f,0.f,0.f};
        #pragma unroll
        for (int kf=0;kf<3;kf++){
            const int kk = kf*32+ko;
            ci=__builtin_amdgcn_mfma_f32_16x16x32_bf16(xinf[kf], ldw(wiht+(size_t)(  0+col)*HD+kk), ci,0,0,0);
            ci=__builtin_amdgcn_mfma_f32_16x16x32_bf16(hf[kf],   ldw(whht+(size_t)(  0+col)*HD+kk), ci,0,0,0);
            cf=__builtin_amdgcn_mfma_f32_16x16x32_bf16(xinf[kf], ldw(wiht+(size_t)( 96+col)*HD+kk), cf,0,0,0);
            cf=__builtin_amdgcn_mfma_f32_16x16x32_bf16(hf[kf],   ldw(whht+(size_t)( 96+col)*HD+kk), cf,0,0,0);
            cg=__builtin_amdgcn_mfma_f32_16x16x32_bf16(xinf[kf], ldw(wiht+(size_t)(192+col)*HD+kk), cg,0,0,0);
            cg=__builtin_amdgcn_mfma_f32_16x16x32_bf16(hf[kf],   ldw(whht+(size_t)(192+col)*HD+kk), cg,0,0,0);
            co=__builtin_amdgcn_mfma_f32_16x16x32_bf16(xinf[kf], ldw(wiht+(size_t)(288+col)*HD+kk), co,0,0,0);
            co=__builtin_amdgcn_mfma_f32_16x16x32_bf16(hf[kf],   ldw(whht+(size_t)(288+col)*HD+kk), co,0,0,0);
        }
        float bi=bih[    col]+bhh[    col];
        float bf=bih[ 96+col]+bhh[ 96+col];
        float bg=bih[192+col]+bhh[192+col];
        float bo=bih[288+col]+bhh[288+col];
        #pragma unroll
        for (int q=0;q<4;q++){
            size_t idx=(size_t)(rowO+q)*HD+col;
            float cold=C[idx];
            float iv=sigf(ci[q]+bi), fv=sigf(cf[q]+bf);
            float gv=tanh_fast(cg[q]+bg), ov=sigf(co[q]+bo);
            float c2v=fv*cold+iv*gv;
            float h2v=ov*tanh_fast(c2v);
            C[idx]=c2v; H[idx]=h2v;
            tr[wave][kgrp*4+q][col]=h2v;
        }
    }
    __syncthreads();

    /* ---- readout MLP ---- */
    #pragma unroll
    for (int kf=0;kf<3;kf++) t[kf]=pack8f(&tr[wave][row16][kf*32+ko]);
    __syncthreads();
    #pragma unroll
    for (int nf=0;nf<6;nf++){
        f32x4 c={0.f,0.f,0.f,0.f};
        #pragma unroll
        for (int kf=0;kf<3;kf++)
            c=__builtin_amdgcn_mfma_f32_16x16x32_bf16(t[kf], ldw(rw1t+(size_t)(nf*16+row16)*HD+kf*32+ko), c,0,0,0);
        float b=rb1[nf*16+row16];
        #pragma unroll
        for (int q=0;q<4;q++) tr[wave][kgrp*4+q][nf*16+row16]=fmaxf(c[q]+b,0.f);
    }
    __syncthreads();
    #pragma unroll
    for (int kf=0;kf<3;kf++) t[kf]=pack8f(&tr[wave][row16][kf*32+ko]);
    __syncthreads();
    #pragma unroll
    for (int nf=0;nf<6;nf++){
        f32x4 c={0.f,0.f,0.f,0.f};
        #pragma unroll
        for (int kf=0;kf<3;kf++)
            c=__builtin_amdgcn_mfma_f32_16x16x32_bf16(t[kf], ldw(rw2t+(size_t)(nf*16+row16)*HD+kf*32+ko), c,0,0,0);
        float b=rb2[nf*16+row16];
        #pragma unroll
        for (int q=0;q<4;q++) tr[wave][kgrp*4+q][nf*16+row16]=fmaxf(c[q]+b,0.f);
    }
    __syncthreads();
    #pragma unroll
    for (int kf=0;kf<3;kf++) t[kf]=pack8f(&tr[wave][row16][kf*32+ko]);
    {
        f32x4 c={0.f,0.f,0.f,0.f};
        #pragma unroll
        for (int kf=0;kf<3;kf++)
            c=__builtin_amdgcn_mfma_f32_16x16x32_bf16(t[kf], ldw(rw3t+(size_t)row16*HD+kf*32+ko), c,0,0,0);
        float b=rb3[row16];
        #pragma unroll
        for (int q=0;q<4;q++)
            out[((size_t)it*Rtot + rowO+q)*Edim + row16]=c[q]+b;
    }
}

extern "C" void kernel_launch(void* const* d_in, const int* in_sizes, int n_in,
                              void* d_out, int out_size, void* d_ws, size_t ws_size,
                              hipStream_t stream) {
    const int*   grids  = (const int*)  d_in[0];
    const int*   nbr    = (const int*)  d_in[1];
    const float* c0     = (const float*)d_in[3];
    const float* embw   = (const float*)d_in[4];
    const float* in_w1  = (const float*)d_in[5];
    const float* in_b1  = (const float*)d_in[6];
    const float* in_w2  = (const float*)d_in[7];
    const float* in_b2  = (const float*)d_in[8];
    const float* in_w3  = (const float*)d_in[9];
    const float* in_b3  = (const float*)d_in[10];
    const float* f_w1   = (const float*)d_in[11];
    const float* f_b1   = (const float*)d_in[12];
    const float* f_w2   = (const float*)d_in[13];
    const float* f_b2   = (const float*)d_in[14];
    const float* f_w3   = (const float*)d_in[15];
    const float* f_b3   = (const float*)d_in[16];
    const float* g_w1   = (const float*)d_in[17];
    const float* g_b1   = (const float*)d_in[18];
    const float* g_w2   = (const float*)d_in[19];
    const float* g_b2   = (const float*)d_in[20];
    const float* g_w3   = (const float*)d_in[21];
    const float* g_b3   = (const float*)d_in[22];
    const float* wih    = (const float*)d_in[23];
    const float* whh    = (const float*)d_in[24];
    const float* bih    = (const float*)d_in[25];
    const float* bhh    = (const float*)d_in[26];
    const float* r_w1   = (const float*)d_in[27];
    const float* r_b1   = (const float*)d_in[28];
    const float* r_w2   = (const float*)d_in[29];
    const float* r_b2   = (const float*)d_in[30];
    const float* r_w3   = (const float*)d_in[31];
    const float* r_b3   = (const float*)d_in[32];

    float* ws = (float*)d_ws;
    float* X  = ws;
    float* H  = ws + (size_t)1*Rtot*HD;
    float* C  = ws + (size_t)2*Rtot*HD;
    float* Aa = ws + (size_t)3*Rtot*HD;
    float* Bm = ws + (size_t)4*Rtot*HD;
    float* Mm = ws + (size_t)5*Rtot*HD;
    __bf16* wt = (__bf16*)(ws + (size_t)6*Rtot*HD);
    float* out = (float*)d_out;

    const __bf16* fw1t = wt + OFF_FW1T;
    const __bf16* fw2t = wt + OFF_FW2T;
    const __bf16* fw3t = wt + OFF_FW3T;
    const __bf16* gw1t = wt + OFF_GW1T;
    const __bf16* gw2t = wt + OFF_GW2T;
    const __bf16* gw3t = wt + OFF_GW3T;
    const __bf16* wiht = wt + OFF_WIHT;
    const __bf16* whht = wt + OFF_WHHT;
    const __bf16* rw1t = wt + OFF_RW1T;
    const __bf16* rw2t = wt + OFF_RW2T;
    const __bf16* rw3t = wt + OFF_RW3T;

    hipLaunchKernelGGL(k_prep, dim3((WT_TOTAL+255)/256), dim3(256), 0, stream,
        f_w1, f_w2, f_w3, g_w1, g_w2, g_w3, wih, whh, r_w1, r_w2, r_w3, wt);

    hipLaunchKernelGGL(k_embed, dim3(Rtot/8), dim3(192), 0, stream,
        grids, embw, in_w1,in_b1,in_w2,in_b2,in_w3,in_b3, c0, X, H, C);

    for (int it=0; it<NITER; ++it){
        hipLaunchKernelGGL(k_ab_mfma, dim3(Rtot/32), dim3(128), 0, stream,
            H, fw1t, Aa, Bm);
        hipLaunchKernelGGL(k_edge_mfma, dim3(Rtot/32), dim3(128), 0, stream,
            Aa, Bm, nbr, f_b1, fw2t, f_b2, fw3t, f_b3, Mm);
        hipLaunchKernelGGL(k_glstm_fused, dim3(Rtot/32), dim3(128), 0, stream,
            X, Mm, H, C,
            gw1t, g_b1, gw2t, g_b2, gw3t, g_b3,
            wiht, whht, bih, bhh,
            rw1t, r_b1, rw2t, r_b2, rw3t, r_b3,
            out, it);
    }
}

// Round 4
// 485.614 us; speedup vs baseline: 7.0307x; 1.2824x over previous
//
#include <hip/hip_runtime.h>
#include <math.h>

#define Bsz 512
#define Nc  81
#define Rtot (Bsz*Nc)     /* 41472 rows */
#define DEG 20
#define Edim 16
#define HD  96
#define NITER 4

typedef __attribute__((ext_vector_type(8))) __bf16 bf16x8;
typedef __attribute__((ext_vector_type(4))) float f32x4;

__device__ __forceinline__ float sigf(float x){ return 1.0f/(1.0f+__expf(-x)); }
__device__ __forceinline__ float tanh_fast(float x){ return 2.0f/(1.0f+__expf(-2.0f*x)) - 1.0f; }

__device__ __forceinline__ unsigned short f2bf(float f){
    union{float f; unsigned u;} v; v.f=f;
    unsigned r = v.u + 0x7fff + ((v.u>>16)&1);
    return (unsigned short)(r>>16);
}
__device__ __forceinline__ float bf2f(unsigned short s){
    union{unsigned u; float f;} v; v.u=((unsigned)s)<<16; return v.f;
}
__device__ __forceinline__ bf16x8 pack8f(const float* x){
    bf16x8 r;
    #pragma unroll
    for (int j=0;j<8;j++) r[j]=(__bf16)x[j];
    return r;
}
__device__ __forceinline__ bf16x8 ldw(const __bf16* p){ return *(const bf16x8*)p; }

/* ---- swizzled LDS tile [16][96] fp32: XOR 16B-chunk index with (row&7) ----
   writes (C-layout scalar): 2-way bank alias (free); reads (row-major b128):
   8 lanes/quad = structural optimum for 64-lane b128. */
__device__ __forceinline__ int swz(int row, int col){
    return row*96 + ((((col>>2) ^ (row&7))<<2) | (col&3));
}
__device__ __forceinline__ void ldtr8(const float* tp, int row, int c, float* o){
    const int r96 = row*96, rho = row&7;
    const float4 a = *(const float4*)(tp + r96 + ((((c>>2)  ) ^ rho)<<2));
    const float4 b = *(const float4*)(tp + r96 + ((((c>>2)+1) ^ rho)<<2));
    o[0]=a.x;o[1]=a.y;o[2]=a.z;o[3]=a.w;o[4]=b.x;o[5]=b.y;o[6]=b.z;o[7]=b.w;
}
__device__ __forceinline__ bf16x8 packtr8(const float* tp, int row, int c){
    float t[8]; ldtr8(tp,row,c,t); return pack8f(t);
}

/* bf16 transposed-weight offsets inside ws (elements) */
#define OFF_FW1T 0          /* [192][96] */
#define OFF_FW2T 18432      /* [96][96]  */
#define OFF_FW3T 27648      /* [96][96]  */
#define OFF_GW1T 36864      /* [96][192] */
#define OFF_GW2T 55296      /* [96][96]  */
#define OFF_GW3T 64512      /* [96][96]  */
#define OFF_WIHT 73728      /* [384][96] */
#define OFF_WHHT 110592     /* [384][96] */
#define OFF_RW1T 147456     /* [96][96]  */
#define OFF_RW2T 156672     /* [96][96]  */
#define OFF_RW3T 165888     /* [16][96]  */
#define WT_TOTAL 167424

/* ---------------- k_prep: one-time bf16 transposed weight conversion ---------------- */
__global__ __launch_bounds__(256) void k_prep(
    const float* __restrict__ fw1, const float* __restrict__ fw2, const float* __restrict__ fw3,
    const float* __restrict__ gw1, const float* __restrict__ gw2, const float* __restrict__ gw3,
    const float* __restrict__ wih, const float* __restrict__ whh,
    const float* __restrict__ rw1, const float* __restrict__ rw2, const float* __restrict__ rw3,
    __bf16* __restrict__ wt)
{
    int i = blockIdx.x*256 + threadIdx.x;
    if (i >= WT_TOTAL) return;
    int j = i;
    if (j < 18432){ int n=j/96, k=j-n*96;
        wt[OFF_FW1T+j] = (__bf16)(n<96 ? fw1[k*96+n] : fw1[(96+k)*96+(n-96)]); return; }
    j -= 18432;
    if (j < 9216){ int n=j/96, k=j-n*96; wt[OFF_FW2T+j]=(__bf16)fw2[k*96+n]; return; }
    j -= 9216;
    if (j < 9216){ int n=j/96, k=j-n*96; wt[OFF_FW3T+j]=(__bf16)fw3[k*96+n]; return; }
    j -= 9216;
    if (j < 18432){ int n=j/192, k=j-n*192; wt[OFF_GW1T+j]=(__bf16)gw1[k*96+n]; return; }
    j -= 18432;
    if (j < 9216){ int n=j/96, k=j-n*96; wt[OFF_GW2T+j]=(__bf16)gw2[k*96+n]; return; }
    j -= 9216;
    if (j < 9216){ int n=j/96, k=j-n*96; wt[OFF_GW3T+j]=(__bf16)gw3[k*96+n]; return; }
    j -= 9216;
    if (j < 36864){ int n=j/96, k=j-n*96; wt[OFF_WIHT+j]=(__bf16)wih[k*384+n]; return; }
    j -= 36864;
    if (j < 36864){ int n=j/96, k=j-n*96; wt[OFF_WHHT+j]=(__bf16)whh[k*384+n]; return; }
    j -= 36864;
    if (j < 9216){ int n=j/96, k=j-n*96; wt[OFF_RW1T+j]=(__bf16)rw1[k*96+n]; return; }
    j -= 9216;
    if (j < 9216){ int n=j/96, k=j-n*96; wt[OFF_RW2T+j]=(__bf16)rw2[k*96+n]; return; }
    j -= 9216;
    { int n=j/96, k=j-n*96; wt[OFF_RW3T+j]=(__bf16)rw3[k*16+n]; }
}

/* ---------------- kernel A: embed + input MLP, init h,c (runs once) ---------------- */
__global__ __launch_bounds__(192) void k_embed(
    const int* __restrict__ grids, const float* __restrict__ embw,
    const float* __restrict__ w1, const float* __restrict__ b1,
    const float* __restrict__ w2, const float* __restrict__ b2,
    const float* __restrict__ w3, const float* __restrict__ b3,
    const float* __restrict__ c0,
    __bf16* __restrict__ X, __bf16* __restrict__ H, float* __restrict__ C)
{
    __shared__ float e[2][4][Edim];
    __shared__ float a0[2][4][HD];
    __shared__ float a1[2][4][HD];
    const int tid = threadIdx.x;
    const int rg = tid / HD, c = tid - rg*HD;
    const int r0 = blockIdx.x*8 + rg*4;

    if (c < Edim) {
        #pragma unroll
        for (int rr=0;rr<4;rr++)
            e[rg][rr][c] = embw[grids[r0+rr]*Edim + c];
    }
    __syncthreads();
    float s0,s1,s2,s3;
    s0=s1=s2=s3=b1[c];
    #pragma unroll
    for (int k=0;k<Edim;k++){
        float w=w1[k*HD+c];
        s0+=e[rg][0][k]*w; s1+=e[rg][1][k]*w;
        s2+=e[rg][2][k]*w; s3+=e[rg][3][k]*w;
    }
    a0[rg][0][c]=fmaxf(s0,0.f); a0[rg][1][c]=fmaxf(s1,0.f);
    a0[rg][2][c]=fmaxf(s2,0.f); a0[rg][3][c]=fmaxf(s3,0.f);
    __syncthreads();
    s0=s1=s2=s3=b2[c];
    #pragma unroll 4
    for (int k=0;k<HD;k++){
        float w=w2[k*HD+c];
        s0+=a0[rg][0][k]*w; s1+=a0[rg][1][k]*w;
        s2+=a0[rg][2][k]*w; s3+=a0[rg][3][k]*w;
    }
    a1[rg][0][c]=fmaxf(s0,0.f); a1[rg][1][c]=fmaxf(s1,0.f);
    a1[rg][2][c]=fmaxf(s2,0.f); a1[rg][3][c]=fmaxf(s3,0.f);
    __syncthreads();
    s0=s1=s2=s3=b3[c];
    #pragma unroll 4
    for (int k=0;k<HD;k++){
        float w=w3[k*HD+c];
        s0+=a1[rg][0][k]*w; s1+=a1[rg][1][k]*w;
        s2+=a1[rg][2][k]*w; s3+=a1[rg][3][k]*w;
    }
    X[(r0+0)*HD+c]=(__bf16)s0; H[(r0+0)*HD+c]=(__bf16)s0; C[(r0+0)*HD+c]=c0[(r0+0)*HD+c];
    X[(r0+1)*HD+c]=(__bf16)s1; H[(r0+1)*HD+c]=(__bf16)s1; C[(r0+1)*HD+c]=c0[(r0+1)*HD+c];
    X[(r0+2)*HD+c]=(__bf16)s2; H[(r0+2)*HD+c]=(__bf16)s2; C[(r0+2)*HD+c]=c0[(r0+2)*HD+c];
    X[(r0+3)*HD+c]=(__bf16)s3; H[(r0+3)*HD+c]=(__bf16)s3; C[(r0+3)*HD+c]=c0[(r0+3)*HD+c];
}

/* ---------------- k_ab: [A|Bm] = h @ fw1 (runs once, before iter 0) ---------------- */
__global__ __launch_bounds__(64) void k_ab(
    const __bf16* __restrict__ H, const __bf16* __restrict__ fw1t,
    __bf16* __restrict__ Ag, __bf16* __restrict__ Bmg)
{
    const int lane = threadIdx.x & 63;
    const int row16 = lane&15, kgrp = lane>>4, ko = kgrp*8;
    const int rowA = blockIdx.x*16 + row16;
    const int rowO = blockIdx.x*16 + kgrp*4;
    bf16x8 hf[3];
    #pragma unroll
    for (int kf=0;kf<3;kf++) hf[kf]=ldw(H + (size_t)rowA*HD + kf*32 + ko);
    #pragma unroll
    for (int nf=0;nf<12;nf++){
        f32x4 c={0.f,0.f,0.f,0.f};
        #pragma unroll
        for (int kf=0;kf<3;kf++)
            c=__builtin_amdgcn_mfma_f32_16x16x32_bf16(hf[kf], ldw(fw1t+(size_t)(nf*16+row16)*HD+kf*32+ko), c, 0,0,0);
        __bf16* dst = (nf<6)? Ag : Bmg;
        int col = ((nf<6)? nf : nf-6)*16 + row16;
        #pragma unroll
        for (int q=0;q<4;q++) dst[(size_t)(rowO+q)*HD+col]=(__bf16)c[q];
    }
}

/* ---------------- k_edge: edge message MLP (A,Bm,M bf16) ---------------- */
__global__ __launch_bounds__(64) void k_edge(
    const __bf16* __restrict__ Ag, const __bf16* __restrict__ Bmg,
    const int* __restrict__ nbr,
    const float* __restrict__ fb1, const __bf16* __restrict__ fw2t,
    const float* __restrict__ fb2, const __bf16* __restrict__ fw3t,
    const float* __restrict__ fb3,
    __bf16* __restrict__ M)
{
    __shared__ float accs[16*96];
    const int lane = threadIdx.x & 63;
    const int row16 = lane&15, kgrp = lane>>4, ko = kgrp*8;
    const int rowA = blockIdx.x*16 + row16;
    const int iI = rowA % Nc;
    const __bf16* BmB = Bmg + (size_t)(rowA - iI)*HD;

    bf16x8 w2f[3][6];
    #pragma unroll
    for (int kf=0; kf<3; kf++)
        #pragma unroll
        for (int nf=0; nf<6; nf++)
            w2f[kf][nf] = ldw(fw2t + (size_t)(nf*16+row16)*HD + kf*32+ko);

    float a[3][8];
    #pragma unroll
    for (int kf=0;kf<3;kf++){
        bf16x8 av = ldw(Ag + (size_t)rowA*HD + kf*32 + ko);
        #pragma unroll
        for (int j=0;j<8;j++) a[kf][j] = (float)av[j] + fb1[kf*32+ko+j];
    }
    float b2c[6], b3c[6];
    #pragma unroll
    for (int nf=0;nf<6;nf++){ b2c[nf]=fb2[nf*16+row16]; b3c[nf]=20.0f*fb3[nf*16+row16]; }

    f32x4 acc[6];
    #pragma unroll
    for (int nf=0;nf<6;nf++) acc[nf]=(f32x4){0.f,0.f,0.f,0.f};

    const int* nrow = nbr + iI*DEG;
    #pragma unroll 2
    for (int d=0; d<DEG; d++){
        int j = nrow[d];
        const __bf16* Vb = BmB + (size_t)j*HD + ko;
        bf16x8 xf[3];
        #pragma unroll
        for (int kf=0;kf<3;kf++){
            bf16x8 v = ldw(Vb + kf*32);
            float t[8];
            #pragma unroll
            for (int jj=0;jj<8;jj++) t[jj]=fmaxf(a[kf][jj] + (float)v[jj], 0.f);
            xf[kf]=pack8f(t);
        }
        f32x4 c[6];
        #pragma unroll
        for (int nf=0;nf<6;nf++) c[nf]=(f32x4){0.f,0.f,0.f,0.f};
        #pragma unroll
        for (int kf=0;kf<3;kf++)
            #pragma unroll
            for (int nf=0;nf<6;nf++)
                c[nf]=__builtin_amdgcn_mfma_f32_16x16x32_bf16(xf[kf],w2f[kf][nf],c[nf],0,0,0);
        #pragma unroll
        for (int nf=0;nf<6;nf++)
            #pragma unroll
            for (int q2=0;q2<4;q2++)
                acc[nf][q2]+=fmaxf(c[nf][q2]+b2c[nf],0.f);
    }

    /* layer 3: in-wave transpose via swizzled LDS, hi/lo bf16 split */
    #pragma unroll
    for (int nf=0;nf<6;nf++)
        #pragma unroll
        for (int q2=0;q2<4;q2++)
            accs[swz(kgrp*4+q2, nf*16+row16)]=acc[nf][q2];
    __syncthreads();

    f32x4 c2[6];
    #pragma unroll
    for (int nf=0;nf<6;nf++) c2[nf]=(f32x4){0.f,0.f,0.f,0.f};
    #pragma unroll
    for (int kf=0;kf<3;kf++){
        float h[8]; ldtr8(accs, row16, kf*32+ko, h);
        bf16x8 hif, lof;
        #pragma unroll
        for (int j=0;j<8;j++){
            unsigned short hs=f2bf(h[j]);
            union{unsigned short s; __bf16 b;} u; u.s=hs;
            hif[j]=u.b; lof[j]=(__bf16)(h[j]-bf2f(hs));
        }
        #pragma unroll
        for (int nf=0;nf<6;nf++){
            bf16x8 w3f = ldw(fw3t + (size_t)(nf*16+row16)*HD + kf*32+ko);
            c2[nf]=__builtin_amdgcn_mfma_f32_16x16x32_bf16(hif,w3f,c2[nf],0,0,0);
            c2[nf]=__builtin_amdgcn_mfma_f32_16x16x32_bf16(lof,w3f,c2[nf],0,0,0);
        }
    }
    const int rowOut = blockIdx.x*16 + kgrp*4;
    #pragma unroll
    for (int nf=0;nf<6;nf++)
        #pragma unroll
        for (int q2=0;q2<4;q2++)
            M[(size_t)(rowOut+q2)*HD + nf*16+row16] = (__bf16)(c2[nf][q2]+b3c[nf]);
}

/* ---------------- k_fused: g-MLP + LSTM + readout + next-iter A/Bm ----------------
   64-thread blocks (1 wave, 2 row-tiles of 16): no cross-wave LDS sharing,
   swizzled in-wave transposes. */
__global__ __launch_bounds__(64) void k_fused(
    const __bf16* __restrict__ Xg, const __bf16* __restrict__ Mg,
    __bf16* __restrict__ Hg, float* __restrict__ Cg,
    __bf16* __restrict__ Ag, __bf16* __restrict__ Bmg,
    const __bf16* __restrict__ wt,
    const float* __restrict__ gb1, const float* __restrict__ gb2, const float* __restrict__ gb3,
    const float* __restrict__ bih, const float* __restrict__ bhh,
    const float* __restrict__ rb1, const float* __restrict__ rb2, const float* __restrict__ rb3,
    float* __restrict__ out, int it)
{
    __shared__ float trs[2][16*96];
    const int lane = threadIdx.x & 63;
    const int row16 = lane&15, kgrp = lane>>4, ko = kgrp*8;
    const int r0 = blockIdx.x*32;
    const int rowA0 = r0+row16,   rowA1 = r0+16+row16;
    const int rowO0 = r0+kgrp*4,  rowO1 = r0+16+kgrp*4;
    float* tp0 = trs[0]; float* tp1 = trs[1];

    const __bf16* fw1t = wt + OFF_FW1T;
    const __bf16* gw1t = wt + OFF_GW1T;
    const __bf16* gw2t = wt + OFF_GW2T;
    const __bf16* gw3t = wt + OFF_GW3T;
    const __bf16* wiht = wt + OFF_WIHT;
    const __bf16* whht = wt + OFF_WHHT;
    const __bf16* rw1t = wt + OFF_RW1T;
    const __bf16* rw2t = wt + OFF_RW2T;
    const __bf16* rw3t = wt + OFF_RW3T;

    /* ---- g layer 1: concat(X,M) @ gw1 ---- */
    bf16x8 xa[6], xb[6];
    #pragma unroll
    for (int kf=0;kf<3;kf++){
        xa[kf]   = ldw(Xg + (size_t)rowA0*HD + kf*32+ko);
        xb[kf]   = ldw(Xg + (size_t)rowA1*HD + kf*32+ko);
        xa[3+kf] = ldw(Mg + (size_t)rowA0*HD + kf*32+ko);
        xb[3+kf] = ldw(Mg + (size_t)rowA1*HD + kf*32+ko);
    }
    #pragma unroll
    for (int nf=0;nf<6;nf++){
        f32x4 c0={0.f,0.f,0.f,0.f}, c1={0.f,0.f,0.f,0.f};
        #pragma unroll
        for (int kf=0;kf<6;kf++){
            bf16x8 wf = ldw(gw1t + (size_t)(nf*16+row16)*192 + kf*32+ko);
            c0=__builtin_amdgcn_mfma_f32_16x16x32_bf16(xa[kf],wf,c0,0,0,0);
            c1=__builtin_amdgcn_mfma_f32_16x16x32_bf16(xb[kf],wf,c1,0,0,0);
        }
        float b=gb1[nf*16+row16];
        #pragma unroll
        for (int q=0;q<4;q++){
            tp0[swz(kgrp*4+q, nf*16+row16)]=fmaxf(c0[q]+b,0.f);
            tp1[swz(kgrp*4+q, nf*16+row16)]=fmaxf(c1[q]+b,0.f);
        }
    }
    __syncthreads();
    /* ---- g layer 2 ---- */
    bf16x8 ta[3], tb[3];
    #pragma unroll
    for (int kf=0;kf<3;kf++){ ta[kf]=packtr8(tp0,row16,kf*32+ko); tb[kf]=packtr8(tp1,row16,kf*32+ko); }
    __syncthreads();
    #pragma unroll
    for (int nf=0;nf<6;nf++){
        f32x4 c0={0.f,0.f,0.f,0.f}, c1={0.f,0.f,0.f,0.f};
        #pragma unroll
        for (int kf=0;kf<3;kf++){
            bf16x8 wf = ldw(gw2t + (size_t)(nf*16+row16)*HD + kf*32+ko);
            c0=__builtin_amdgcn_mfma_f32_16x16x32_bf16(ta[kf],wf,c0,0,0,0);
            c1=__builtin_amdgcn_mfma_f32_16x16x32_bf16(tb[kf],wf,c1,0,0,0);
        }
        float b=gb2[nf*16+row16];
        #pragma unroll
        for (int q=0;q<4;q++){
            tp0[swz(kgrp*4+q, nf*16+row16)]=fmaxf(c0[q]+b,0.f);
            tp1[swz(kgrp*4+q, nf*16+row16)]=fmaxf(c1[q]+b,0.f);
        }
    }
    __syncthreads();
    /* ---- g layer 3 (linear) -> x_in ---- */
    #pragma unroll
    for (int kf=0;kf<3;kf++){ ta[kf]=packtr8(tp0,row16,kf*32+ko); tb[kf]=packtr8(tp1,row16,kf*32+ko); }
    __syncthreads();
    #pragma unroll
    for (int nf=0;nf<6;nf++){
        f32x4 c0={0.f,0.f,0.f,0.f}, c1={0.f,0.f,0.f,0.f};
        #pragma unroll
        for (int kf=0;kf<3;kf++){
            bf16x8 wf = ldw(gw3t + (size_t)(nf*16+row16)*HD + kf*32+ko);
            c0=__builtin_amdgcn_mfma_f32_16x16x32_bf16(ta[kf],wf,c0,0,0,0);
            c1=__builtin_amdgcn_mfma_f32_16x16x32_bf16(tb[kf],wf,c1,0,0,0);
        }
        float b=gb3[nf*16+row16];
        #pragma unroll
        for (int q=0;q<4;q++){
            tp0[swz(kgrp*4+q, nf*16+row16)]=c0[q]+b;
            tp1[swz(kgrp*4+q, nf*16+row16)]=c1[q]+b;
        }
    }
    __syncthreads();
    bf16x8 xf0[3], xf1[3];
    #pragma unroll
    for (int kf=0;kf<3;kf++){ xf0[kf]=packtr8(tp0,row16,kf*32+ko); xf1[kf]=packtr8(tp1,row16,kf*32+ko); }
    __syncthreads();

    /* ---- LSTM gates ---- */
    bf16x8 hfa[3], hfb[3];
    #pragma unroll
    for (int kf=0;kf<3;kf++){
        hfa[kf]=ldw(Hg + (size_t)rowA0*HD + kf*32+ko);
        hfb[kf]=ldw(Hg + (size_t)rowA1*HD + kf*32+ko);
    }
    #pragma unroll 2
    for (int nf=0;nf<6;nf++){
        const int col = nf*16+row16;
        f32x4 g0[4], g1[4];
        #pragma unroll
        for (int g=0;g<4;g++){ g0[g]=(f32x4){0.f,0.f,0.f,0.f}; g1[g]=(f32x4){0.f,0.f,0.f,0.f}; }
        #pragma unroll
        for (int g=0;g<4;g++){
            #pragma unroll
            for (int kf=0;kf<3;kf++){
                const int kk = kf*32+ko;
                bf16x8 wx = ldw(wiht + (size_t)(g*96+col)*HD + kk);
                bf16x8 wh = ldw(whht + (size_t)(g*96+col)*HD + kk);
                g0[g]=__builtin_amdgcn_mfma_f32_16x16x32_bf16(xf0[kf],wx,g0[g],0,0,0);
                g0[g]=__builtin_amdgcn_mfma_f32_16x16x32_bf16(hfa[kf],wh,g0[g],0,0,0);
                g1[g]=__builtin_amdgcn_mfma_f32_16x16x32_bf16(xf1[kf],wx,g1[g],0,0,0);
                g1[g]=__builtin_amdgcn_mfma_f32_16x16x32_bf16(hfb[kf],wh,g1[g],0,0,0);
            }
        }
        float bi=bih[    col]+bhh[    col];
        float bf=bih[ 96+col]+bhh[ 96+col];
        float bg=bih[192+col]+bhh[192+col];
        float bo=bih[288+col]+bhh[288+col];
        #pragma unroll
        for (int q=0;q<4;q++){
            {
                size_t idx=(size_t)(rowO0+q)*HD+col;
                float cold=Cg[idx];
                float iv=sigf(g0[0][q]+bi), fv=sigf(g0[1][q]+bf);
                float gv=tanh_fast(g0[2][q]+bg), ov=sigf(g0[3][q]+bo);
                float c2v=fv*cold+iv*gv;
                float h2v=ov*tanh_fast(c2v);
                Cg[idx]=c2v; Hg[idx]=(__bf16)h2v;
                tp0[swz(kgrp*4+q,col)]=h2v;
            }
            {
                size_t idx=(size_t)(rowO1+q)*HD+col;
                float cold=Cg[idx];
                float iv=sigf(g1[0][q]+bi), fv=sigf(g1[1][q]+bf);
                float gv=tanh_fast(g1[2][q]+bg), ov=sigf(g1[3][q]+bo);
                float c2v=fv*cold+iv*gv;
                float h2v=ov*tanh_fast(c2v);
                Cg[idx]=c2v; Hg[idx]=(__bf16)h2v;
                tp1[swz(kgrp*4+q,col)]=h2v;
            }
        }
    }
    __syncthreads();

    /* ---- h2 fragments (consumed by next-iter A/Bm AND readout layer 1) ---- */
    bf16x8 hf0[3], hf1[3];
    #pragma unroll
    for (int kf=0;kf<3;kf++){ hf0[kf]=packtr8(tp0,row16,kf*32+ko); hf1[kf]=packtr8(tp1,row16,kf*32+ko); }
    __syncthreads();

    /* ---- next-iter [A|Bm] = h2 @ fw1 ---- */
    if (it < NITER-1){
        #pragma unroll
        for (int nf=0;nf<12;nf++){
            f32x4 c0={0.f,0.f,0.f,0.f}, c1={0.f,0.f,0.f,0.f};
            #pragma unroll
            for (int kf=0;kf<3;kf++){
                bf16x8 wf = ldw(fw1t + (size_t)(nf*16+row16)*HD + kf*32+ko);
                c0=__builtin_amdgcn_mfma_f32_16x16x32_bf16(hf0[kf],wf,c0,0,0,0);
                c1=__builtin_amdgcn_mfma_f32_16x16x32_bf16(hf1[kf],wf,c1,0,0,0);
            }
            __bf16* dst = (nf<6)? Ag : Bmg;
            int col = ((nf<6)? nf : nf-6)*16 + row16;
            #pragma unroll
            for (int q=0;q<4;q++){
                dst[(size_t)(rowO0+q)*HD+col]=(__bf16)c0[q];
                dst[(size_t)(rowO1+q)*HD+col]=(__bf16)c1[q];
            }
        }
    }

    /* ---- readout layer 1 ---- */
    #pragma unroll
    for (int nf=0;nf<6;nf++){
        f32x4 c0={0.f,0.f,0.f,0.f}, c1={0.f,0.f,0.f,0.f};
        #pragma unroll
        for (int kf=0;kf<3;kf++){
            bf16x8 wf = ldw(rw1t + (size_t)(nf*16+row16)*HD + kf*32+ko);
            c0=__builtin_amdgcn_mfma_f32_16x16x32_bf16(hf0[kf],wf,c0,0,0,0);
            c1=__builtin_amdgcn_mfma_f32_16x16x32_bf16(hf1[kf],wf,c1,0,0,0);
        }
        float b=rb1[nf*16+row16];
        #pragma unroll
        for (int q=0;q<4;q++){
            tp0[swz(kgrp*4+q, nf*16+row16)]=fmaxf(c0[q]+b,0.f);
            tp1[swz(kgrp*4+q, nf*16+row16)]=fmaxf(c1[q]+b,0.f);
        }
    }
    __syncthreads();
    /* ---- readout layer 2 ---- */
    #pragma unroll
    for (int kf=0;kf<3;kf++){ ta[kf]=packtr8(tp0,row16,kf*32+ko); tb[kf]=packtr8(tp1,row16,kf*32+ko); }
    __syncthreads();
    #pragma unroll
    for (int nf=0;nf<6;nf++){
        f32x4 c0={0.f,0.f,0.f,0.f}, c1={0.f,0.f,0.f,0.f};
        #pragma unroll
        for (int kf=0;kf<3;kf++){
            bf16x8 wf = ldw(rw2t + (size_t)(nf*16+row16)*HD + kf*32+ko);
            c0=__builtin_amdgcn_mfma_f32_16x16x32_bf16(ta[kf],wf,c0,0,0,0);
            c1=__builtin_amdgcn_mfma_f32_16x16x32_bf16(tb[kf],wf,c1,0,0,0);
        }
        float b=rb2[nf*16+row16];
        #pragma unroll
        for (int q=0;q<4;q++){
            tp0[swz(kgrp*4+q, nf*16+row16)]=fmaxf(c0[q]+b,0.f);
            tp1[swz(kgrp*4+q, nf*16+row16)]=fmaxf(c1[q]+b,0.f);
        }
    }
    __syncthreads();
    /* ---- readout layer 3 -> out ---- */
    #pragma unroll
    for (int kf=0;kf<3;kf++){ ta[kf]=packtr8(tp0,row16,kf*32+ko); tb[kf]=packtr8(tp1,row16,kf*32+ko); }
    {
        f32x4 c0={0.f,0.f,0.f,0.f}, c1={0.f,0.f,0.f,0.f};
        #pragma unroll
        for (int kf=0;kf<3;kf++){
            bf16x8 wf = ldw(rw3t + (size_t)row16*HD + kf*32+ko);
            c0=__builtin_amdgcn_mfma_f32_16x16x32_bf16(ta[kf],wf,c0,0,0,0);
            c1=__builtin_amdgcn_mfma_f32_16x16x32_bf16(tb[kf],wf,c1,0,0,0);
        }
        float b=rb3[row16];
        #pragma unroll
        for (int q=0;q<4;q++){
            out[((size_t)it*Rtot + rowO0+q)*Edim + row16]=c0[q]+b;
            out[((size_t)it*Rtot + rowO1+q)*Edim + row16]=c1[q]+b;
        }
    }
}

extern "C" void kernel_launch(void* const* d_in, const int* in_sizes, int n_in,
                              void* d_out, int out_size, void* d_ws, size_t ws_size,
                              hipStream_t stream) {
    const int*   grids  = (const int*)  d_in[0];
    const int*   nbr    = (const int*)  d_in[1];
    const float* c0     = (const float*)d_in[3];
    const float* embw   = (const float*)d_in[4];
    const float* in_w1  = (const float*)d_in[5];
    const float* in_b1  = (const float*)d_in[6];
    const float* in_w2  = (const float*)d_in[7];
    const float* in_b2  = (const float*)d_in[8];
    const float* in_w3  = (const float*)d_in[9];
    const float* in_b3  = (const float*)d_in[10];
    const float* f_w1   = (const float*)d_in[11];
    const float* f_b1   = (const float*)d_in[12];
    const float* f_w2   = (const float*)d_in[13];
    const float* f_b2   = (const float*)d_in[14];
    const float* f_w3   = (const float*)d_in[15];
    const float* f_b3   = (const float*)d_in[16];
    const float* g_b1   = (const float*)d_in[18];
    const float* g_w1   = (const float*)d_in[17];
    const float* g_w2   = (const float*)d_in[19];
    const float* g_b2   = (const float*)d_in[20];
    const float* g_w3   = (const float*)d_in[21];
    const float* g_b3   = (const float*)d_in[22];
    const float* wih    = (const float*)d_in[23];
    const float* whh    = (const float*)d_in[24];
    const float* bih    = (const float*)d_in[25];
    const float* bhh    = (const float*)d_in[26];
    const float* r_w1   = (const float*)d_in[27];
    const float* r_b1   = (const float*)d_in[28];
    const float* r_w2   = (const float*)d_in[29];
    const float* r_b2   = (const float*)d_in[30];
    const float* r_w3   = (const float*)d_in[31];
    const float* r_b3   = (const float*)d_in[32];

    /* workspace layout (all 4B-aligned) */
    __bf16* Xb = (__bf16*)d_ws;                          /* Rtot*96 bf16 */
    __bf16* Hb = Xb + (size_t)Rtot*HD;
    float*  Cw = (float*)(Hb + (size_t)Rtot*HD);         /* Rtot*96 f32  */
    __bf16* Aa = (__bf16*)(Cw + (size_t)Rtot*HD);
    __bf16* Bm = Aa + (size_t)Rtot*HD;
    __bf16* Mm = Bm + (size_t)Rtot*HD;
    __bf16* wt = Mm + (size_t)Rtot*HD;
    float* out = (float*)d_out;

    const __bf16* fw1t = wt + OFF_FW1T;
    const __bf16* fw2t = wt + OFF_FW2T;
    const __bf16* fw3t = wt + OFF_FW3T;

    hipLaunchKernelGGL(k_prep, dim3((WT_TOTAL+255)/256), dim3(256), 0, stream,
        f_w1, f_w2, f_w3, g_w1, g_w2, g_w3, wih, whh, r_w1, r_w2, r_w3, wt);

    hipLaunchKernelGGL(k_embed, dim3(Rtot/8), dim3(192), 0, stream,
        grids, embw, in_w1,in_b1,in_w2,in_b2,in_w3,in_b3, c0, Xb, Hb, Cw);

    hipLaunchKernelGGL(k_ab, dim3(Rtot/16), dim3(64), 0, stream,
        Hb, fw1t, Aa, Bm);

    for (int it=0; it<NITER; ++it){
        hipLaunchKernelGGL(k_edge, dim3(Rtot/16), dim3(64), 0, stream,
            Aa, Bm, nbr, f_b1, fw2t, f_b2, fw3t, f_b3, Mm);
        hipLaunchKernelGGL(k_fused, dim3(Rtot/32), dim3(64), 0, stream,
            Xb, Mm, Hb, Cw, Aa, Bm, wt,
            g_b1, g_b2, g_b3, bih, bhh, r_b1, r_b2, r_b3,
            out, it);
    }
}